// Round 7
// baseline (413.496 us; speedup 1.0000x reference)
//
#include <hip/hip_runtime.h>
#include <math.h>

#define NCLS 64
#define KS 5
#define DD 256
#define NQ 8192   // NCLS*128
#define KNB 10
#define QK 12     // per-chunk candidate list depth (need >=10 for exact containment)
#define NCH 8     // column chunks per row (1024 cols each)
#define CAND 96   // NCH * QK

typedef __attribute__((ext_vector_type(8))) short short8;   // 8 bf16 bit-patterns (4 VGPRs)
typedef __attribute__((ext_vector_type(4))) float f32x4;    // MFMA C/D frag

// row index in x (fp32 row units) of query g
__device__ __forceinline__ int qrow(int g) { return (g >> 7) * 133 + KS + (g & 127); }

__device__ __forceinline__ unsigned short bf16_rne(float f) {
    unsigned int u = __float_as_uint(f);
    u += 0x7fffu + ((u >> 16) & 1u);
    return (unsigned short)(u >> 16);
}

__device__ __forceinline__ float blk_reduce_sum(float v, float* red) {
    int t = threadIdx.x;
    red[t] = v; __syncthreads();
    for (int off = 128; off > 0; off >>= 1) {
        if (t < off) red[t] += red[t + off];
        __syncthreads();
    }
    float r = red[0];
    __syncthreads();
    return r;
}

__device__ __forceinline__ float blk_reduce_max(float v, float* red) {
    int t = threadIdx.x;
    red[t] = v; __syncthreads();
    for (int off = 128; off > 0; off >>= 1) {
        if (t < off) red[t] = fmaxf(red[t], red[t + off]);
        __syncthreads();
    }
    float r = red[0];
    __syncthreads();
    return r;
}

// ---------- K1: proto, pn, self_sim ----------
__global__ __launch_bounds__(256) void proto_kernel(const float* __restrict__ x,
                                                    float* proto, float* pn, float* selfs) {
    __shared__ float red[256];
    int c = blockIdx.x, t = threadIdx.x;
    float s = 0.f;
    for (int j = 0; j < KS; j++) s += x[(long)(c * 133 + j) * DD + t];
    float p = s / 5.0f;
    proto[c * DD + t] = p;
    float n2 = blk_reduce_sum(p * p, red);
    float pv = p / sqrtf(n2);
    pn[c * DD + t] = pv;
    float ss = blk_reduce_sum(pv * pv, red);
    if (t == 0) selfs[c] = ss;
}

// ---------- K2: FUSED split + pre_sim argmax per query ----------
// Absorbs split_kernel: the x row is loaded once; norm -> xh (normalized bf16)
// + qInv; then the 64-class cosine argmax using inv directly.
__global__ __launch_bounds__(256) void presim_kernel(const float* __restrict__ x,
                                                     const float* __restrict__ pn,
                                                     unsigned short* __restrict__ xh,
                                                     float* __restrict__ qInv,
                                                     float* pre_max, int* pre_label) {
    __shared__ __align__(16) float qs[256];
    __shared__ float red[256];
    __shared__ float part[256];
    __shared__ float sims[64];
    int g = blockIdx.x, t = threadIdx.x;
    float v = x[(long)qrow(g) * DD + t];
    qs[t] = v;
    float n2 = blk_reduce_sum(v * v, red);   // barrier publishes qs too
    float inv = 1.f / sqrtf(n2);
    xh[g * DD + t] = bf16_rne(v * inv);
    if (t == 0) qInv[g] = inv;
    int c = t >> 2, tl = t & 3;
    float s = 0.f;
    const float4* qp = (const float4*)(qs + tl * 64);
    const float4* pp = (const float4*)(pn + c * DD + tl * 64);
    #pragma unroll
    for (int u4 = 0; u4 < 16; u4++) {
        float4 a = qp[u4], b = pp[u4];
        s += a.x * b.x; s += a.y * b.y; s += a.z * b.z; s += a.w * b.w;
    }
    part[t] = s; __syncthreads();
    if (tl == 0) sims[c] = part[t] + part[t + 1] + part[t + 2] + part[t + 3];
    __syncthreads();
    if (t == 0) {
        float best = sims[0]; int bi = 0;
        for (int c2 = 1; c2 < 64; c2++)
            if (sims[c2] > best) { best = sims[c2]; bi = c2; }
        pre_max[g] = best * inv;
        pre_label[g] = bi;
    }
}

// ---------- K3: adapted prototypes — LDS-compacted member list ----------
__global__ __launch_bounds__(256) void adapt_proto_kernel(const float* __restrict__ x,
                                                          const float* __restrict__ proto,
                                                          const float* __restrict__ selfs,
                                                          const float* __restrict__ pre_max,
                                                          const int* __restrict__ pre_label,
                                                          float* apn) {
    __shared__ int lst[NQ];
    __shared__ float red[256];
    __shared__ int cnt_s;
    int c = blockIdx.x, t = threadIdx.x;
    if (t == 0) cnt_s = 0;
    __syncthreads();
    float lm = -INFINITY;
    for (int g = t; g < NQ; g += 256) {
        if (pre_label[g] == c) {
            int p = atomicAdd(&cnt_s, 1);
            lst[p] = g;
            lm = fmaxf(lm, pre_max[g]);
        }
    }
    float m = fmaxf(blk_reduce_max(lm, red), selfs[c]);   // barrier publishes lst/cnt_s
    int cnt = cnt_s;
    float ls = 0.f;
    for (int e = t; e < cnt; e += 256) ls += expf(pre_max[lst[e]] - m);
    float es = expf(selfs[c] - m);
    float Z = blk_reduce_sum(ls, red) + es;
    float a0 = es * proto[c * DD + t], a1 = 0.f, a2 = 0.f, a3 = 0.f;
    int e = 0;
    for (; e + 3 < cnt; e += 4) {
        int g0 = lst[e], g1 = lst[e + 1], g2 = lst[e + 2], g3 = lst[e + 3];
        float w0 = expf(pre_max[g0] - m), w1 = expf(pre_max[g1] - m);
        float w2 = expf(pre_max[g2] - m), w3 = expf(pre_max[g3] - m);
        a0 += w0 * x[(long)qrow(g0) * DD + t];
        a1 += w1 * x[(long)qrow(g1) * DD + t];
        a2 += w2 * x[(long)qrow(g2) * DD + t];
        a3 += w3 * x[(long)qrow(g3) * DD + t];
    }
    for (; e < cnt; e++) {
        int g0 = lst[e];
        a0 += expf(pre_max[g0] - m) * x[(long)qrow(g0) * DD + t];
    }
    float ap = ((a0 + a1) + (a2 + a3)) / Z;
    float n2 = blk_reduce_sum(ap * ap, red);
    apn[c * DD + t] = ap / sqrtf(n2);
}

// ---------- K4: bf16 MFMA coarse cosines — 32 QUERIES/WAVE, LDS-staged ----------
// R6 counters: 10MB LDS traffic/CU (~50us at 85B/cyc) was half of simtopk's
// 103us -- all 4 waves re-read each tile for only 16 queries each. Fix: each
// lane carries TWO query B-fragments (qh0/qh1, 64 VGPR; cap 256 via
// __launch_bounds__(256,2), occupancy is grid-limited anyway) and issues 2
// MFMAs per LDS read. Blocks cover 128 query rows; grid 64x8=512 (2/CU).
// Per-CU LDS traffic: 2 blocks x (4w x 64t x 8KB + 64t x 8KB) = 5MB (halved).
#define INSERT_KEY(KEYS, KEY)                                                      \
    if ((KEY) > KEYS[QK - 1]) {                                                    \
        unsigned int ck = (KEY);                                                   \
        _Pragma("unroll")                                                          \
        for (int p = 0; p < QK; ++p) {                                             \
            bool sw = ck > KEYS[p];                                                \
            unsigned int tmp = KEYS[p];                                            \
            KEYS[p] = sw ? ck : KEYS[p];                                           \
            ck = sw ? tmp : ck;                                                    \
        }                                                                          \
    }

#define COMPUTE_TILE_L(LBUF, TILE)                                                 \
    {                                                                              \
        f32x4 acc0 = {0.f, 0.f, 0.f, 0.f};                                         \
        f32x4 acc1 = {0.f, 0.f, 0.f, 0.f};                                         \
        _Pragma("unroll")                                                          \
        for (int kc = 0; kc < 8; kc++) {                                           \
            short8 cf = *(const short8*)((LBUF) + ((nn << 8) + (((kc * 4 + qd) ^ xm) << 3))); \
            acc0 = __builtin_amdgcn_mfma_f32_16x16x32_bf16(cf, qh0[kc], acc0, 0, 0, 0); \
            acc1 = __builtin_amdgcn_mfma_f32_16x16x32_bf16(cf, qh1[kc], acc1, 0, 0, 0); \
        }                                                                          \
        _Pragma("unroll")                                                          \
        for (int r = 0; r < 4; ++r) {                                              \
            unsigned int cid = (unsigned int)((TILE) * 16 + 4 * qd + r);           \
            unsigned int u0k = __float_as_uint(acc0[r]);                           \
            unsigned int k0 = u0k ^ (unsigned int)(((int)u0k >> 31) | 0x80000000); \
            k0 = (k0 & 0xFFFFFC00u) | cid;                                         \
            INSERT_KEY(keys0, k0)                                                  \
            unsigned int u1k = __float_as_uint(acc1[r]);                           \
            unsigned int k1 = u1k ^ (unsigned int)(((int)u1k >> 31) | 0x80000000); \
            k1 = (k1 & 0xFFFFFC00u) | cid;                                         \
            INSERT_KEY(keys1, k1)                                                  \
        }                                                                          \
    }

#define GLOAD(RA, RB, TL)                                                          \
    {                                                                              \
        const unsigned short* tb = xh + ((size_t)(col0 + (TL) * 16) << 8);         \
        RA = *(const uint4*)(tb + (G0 << 3));                                      \
        RB = *(const uint4*)(tb + (G1 << 3));                                      \
    }

#define DSWRITE(LBUF, RA, RB)                                                      \
    {                                                                              \
        *(uint4*)((LBUF) + (u0 << 3)) = RA;                                        \
        *(uint4*)((LBUF) + (u1 << 3)) = RB;                                        \
    }

__global__ __launch_bounds__(256, 2) void simtopk_kernel(const unsigned short* __restrict__ xh,
                                                         int* __restrict__ topi4) {
    __shared__ uint4 smem4[1664];   // 26.6 KB: tiles use [0,1024); dump alias needs 1664
    unsigned short* T0 = (unsigned short*)smem4;
    unsigned short* T1 = (unsigned short*)smem4 + 4096;

    const int t = threadIdx.x;
    const int b = blockIdx.x;
    const int rb = b >> 3;          // 64 row-blocks of 128 rows
    const int ch = b & 7;           // column chunk (== XCD id under round-robin: L2-local)
    const int row0 = rb * 128;
    const int col0 = ch * 1024;

    const int wv = t >> 6;
    const int lane = t & 63;
    const int qd = lane >> 4;
    const int nn = lane & 15;
    const int xm = nn & 7;

    // staging geometry: tile = 512 x 16B units; thread handles G0=t, G1=256+t
    const int G0 = t, G1 = 256 + t;
    const int r0r = G0 >> 5, c0u = G0 & 31;
    const int u0 = r0r * 32 + (c0u ^ (r0r & 7));
    const int r1r = G1 >> 5, c1u = G1 & 31;
    const int u1 = r1r * 32 + (c1u ^ (r1r & 7));

    // TWO query groups per wave (rows wv*32+nn and wv*32+16+nn)
    const int arow0 = (row0 + wv * 32 + nn) * DD;
    const int arow1 = (row0 + wv * 32 + 16 + nn) * DD;
    short8 qh0[8], qh1[8];
    #pragma unroll
    for (int kc = 0; kc < 8; kc++) {
        qh0[kc] = *(const short8*)(xh + arow0 + kc * 32 + qd * 8);
        qh1[kc] = *(const short8*)(xh + arow1 + kc * 32 + qd * 8);
    }

    unsigned int keys0[QK], keys1[QK];
    #pragma unroll
    for (int s = 0; s < QK; s++) { keys0[s] = 0u; keys1[s] = 0u; }

    uint4 RA, RB;
    GLOAD(RA, RB, 0)
    DSWRITE(T0, RA, RB)
    __syncthreads();                         // T0 ready

    #pragma unroll 1
    for (int t2 = 0; t2 < 32; ++t2) {
        GLOAD(RA, RB, 2 * t2 + 1)            // issue early (hides under compute)
        COMPUTE_TILE_L(T0, 2 * t2)
        __syncthreads();                     // all waves done reading T1 (prev iter)
        DSWRITE(T1, RA, RB)
        if (t2 < 31) GLOAD(RA, RB, 2 * t2 + 2)
        __syncthreads();                     // T1 ready
        COMPUTE_TILE_L(T1, 2 * t2 + 1)
        __syncthreads();                     // all waves done reading T0
        if (t2 < 31) { DSWRITE(T0, RA, RB) }
        __syncthreads();                     // T0 ready
    }

    // dump both groups (wave-private regions; in-order DS, no barrier), then
    // 32 lanes merge: lanes 0..15 group0 queries, lanes 16..31 group1.
    unsigned int* dw = (unsigned int*)smem4 + wv * 1664;
    #pragma unroll
    for (int s = 0; s < QK; s++) dw[lane * 13 + s] = keys0[s];
    unsigned int* dw1 = dw + 832;
    #pragma unroll
    for (int s = 0; s < QK; s++) dw1[lane * 13 + s] = keys1[s];
    if (lane < 32) {
        const int grp = lane >> 4;
        const int qq = lane & 15;
        unsigned int* dm = dw + grp * 832;
        const int g = row0 + wv * 32 + grp * 16 + qq;
        const int b0 = (qq +  0) * 13;
        const int b1 = (qq + 16) * 13;
        const int b2 = (qq + 32) * 13;
        const int b3 = (qq + 48) * 13;
        int p0 = 0, p1 = 0, p2 = 0, p3 = 0;
        for (int s = 0; s < QK; s++) {
            unsigned int v0 = (p0 < QK) ? dm[b0 + p0] : 0u;
            unsigned int v1 = (p1 < QK) ? dm[b1 + p1] : 0u;
            unsigned int v2 = (p2 < QK) ? dm[b2 + p2] : 0u;
            unsigned int v3 = (p3 < QK) ? dm[b3 + p3] : 0u;
            unsigned int bv = v0; int bw = 0;
            if (v1 > bv) { bv = v1; bw = 1; }
            if (v2 > bv) { bv = v2; bw = 2; }
            if (v3 > bv) { bv = v3; bw = 3; }
            topi4[g * CAND + ch * QK + s] = col0 + (int)(bv & 1023u);
            if (bw == 0) p0++; else if (bw == 1) p1++; else if (bw == 2) p2++; else p3++;
        }
    }
}

// ---------- K5a: exact fp32 rescoring — wave-per-24-candidates, max TLP ----------
__global__ __launch_bounds__(64, 8) void rescore_kernel(const float* __restrict__ x,
                                                        const float* __restrict__ qInv,
                                                        const int* __restrict__ topi4,
                                                        float* __restrict__ scoreb) {
    const int wid = blockIdx.x;
    const int g = wid >> 2;
    const int w = wid & 3;            // wave's candidate group [24w, 24w+24)
    const int lane = threadIdx.x;
    const float4 a4 = *(const float4*)(x + (long)qrow(g) * DD + lane * 4);
    const float qg = qInv[g];
    const int cb = g * CAND + w * 24;
    #pragma unroll 1
    for (int r = 0; r < 3; ++r) {
        const int c0 = cb + r * 8;
        int jj[8];
        #pragma unroll
        for (int u = 0; u < 8; u++) {
            int j = topi4[c0 + u];
            jj[u] = __builtin_amdgcn_readfirstlane(((unsigned)j < NQ) ? j : 0);
        }
        float4 b[8];
        #pragma unroll
        for (int u = 0; u < 8; u++)
            b[u] = *(const float4*)(x + (long)qrow(jj[u]) * DD + lane * 4);
        float p[8];
        #pragma unroll
        for (int u = 0; u < 8; u++)
            p[u] = a4.x * b[u].x + a4.y * b[u].y + a4.z * b[u].z + a4.w * b[u].w;
        #pragma unroll
        for (int off = 32; off > 0; off >>= 1) {
            #pragma unroll
            for (int u = 0; u < 8; u++) p[u] += __shfl_xor(p[u], off);
        }
        if (lane == 0) {
            #pragma unroll
            for (int u = 0; u < 8; u++) scoreb[c0 + u] = p[u] * qInv[jj[u]] * qg;
        }
    }
}

// ---------- K5b: wave-parallel top-10 of the 96 rescored candidates ----------
__global__ __launch_bounds__(64) void topk_kernel(const float* __restrict__ scoreb,
                                                  const int* __restrict__ topi4,
                                                  float* __restrict__ topv,
                                                  int* __restrict__ topi) {
    const int g = blockIdx.x;
    const int lane = threadIdx.x;
    float v0 = scoreb[g * CAND + lane];
    int j0 = topi4[g * CAND + lane];
    int i0 = ((unsigned)j0 < NQ) ? j0 : 0;
    float v1 = -INFINITY; int i1 = 0x7fffffff;
    if (lane < CAND - 64) {
        v1 = scoreb[g * CAND + 64 + lane];
        int j1 = topi4[g * CAND + 64 + lane];
        i1 = ((unsigned)j1 < NQ) ? j1 : 0;
    }
    #pragma unroll 1
    for (int s = 0; s < KNB; ++s) {
        bool sel1 = (v1 > v0) || (v1 == v0 && i1 < i0);
        float bv = sel1 ? v1 : v0;
        int   bi = sel1 ? i1 : i0;
        #pragma unroll
        for (int off = 32; off > 0; off >>= 1) {
            float ov = __shfl_xor(bv, off);
            int   oi = __shfl_xor(bi, off);
            bool take = (ov > bv) || (ov == bv && oi < bi);
            bv = take ? ov : bv;
            bi = take ? oi : bi;
        }
        if (lane == 0) { topv[g * KNB + s] = bv; topi[g * KNB + s] = bi; }
        if (i0 == bi) v0 = -INFINITY;
        if (i1 == bi) v1 = -INFINITY;
    }
}

// ---------- K6: mutual-kNN softmax, adapted query, final cos sims ----------
__global__ __launch_bounds__(256) void final_kernel(const float* __restrict__ x,
                                                    const float* __restrict__ apn,
                                                    const float* __restrict__ topv,
                                                    const int* __restrict__ topi,
                                                    const float* __restrict__ tao_raw,
                                                    float* out) {
    __shared__ float tv[KNB]; __shared__ int ti[KNB]; __shared__ float w[KNB];
    __shared__ __align__(16) float aq[256]; __shared__ float red[256];
    int i = blockIdx.x, t = threadIdx.x;
    if (t < KNB) {
        tv[t] = topv[i * KNB + t];
        int j = topi[i * KNB + t];
        ti[t] = ((unsigned)j < NQ) ? j : 0;
    }
    __syncthreads();
    if (t < KNB) {
        int j = ti[t];
        bool mut = false;
        for (int s = 0; s < KNB; s++) mut = mut || (topi[j * KNB + s] == i);
        w[t] = mut ? tv[t] : -INFINITY;
    }
    __syncthreads();
    if (t == 0) {
        float m = -INFINITY;
        for (int s = 0; s < KNB; s++) m = fmaxf(m, w[s]);
        float e[KNB]; float Z = 0.f;
        for (int s = 0; s < KNB; s++) { e[s] = expf(w[s] - m); Z += e[s]; }
        for (int s = 0; s < KNB; s++) w[s] = e[s] / Z;
    }
    __syncthreads();
    float a = 0.f;
    for (int s = 0; s < KNB; s++) {
        float ws = w[s];
        if (ws != 0.f) a += ws * x[(long)qrow(ti[s]) * DD + t];
    }
    aq[t] = a;
    float n2 = blk_reduce_sum(a * a, red);
    float inv = 1.f / sqrtf(n2);
    int c = t >> 2, tl = t & 3;
    float sdot = 0.f;
    const float4* ap4 = (const float4*)(apn + c * DD + tl * 64);
    const float4* aq4 = (const float4*)(aq + tl * 64);
    #pragma unroll
    for (int u4 = 0; u4 < 16; u4++) {
        float4 av = aq4[u4], pv = ap4[u4];
        sdot += av.x * pv.x; sdot += av.y * pv.y; sdot += av.z * pv.z; sdot += av.w * pv.w;
    }
    red[t] = sdot; __syncthreads();
    if (tl == 0) {
        float sv = red[t] + red[t + 1] + red[t + 2] + red[t + 3];
        out[i * NCLS + c] = tao_raw[0] * sv * inv;
    }
}

extern "C" void kernel_launch(void* const* d_in, const int* in_sizes, int n_in,
                              void* d_out, int out_size, void* d_ws, size_t ws_size,
                              hipStream_t stream) {
    (void)in_sizes; (void)n_in; (void)out_size;
    const float* x   = (const float*)d_in[0];
    const float* tao = (const float*)d_in[1];
    float* out = (float*)d_out;

    char* ws = (char*)d_ws;
    size_t off = 0;
    auto carve = [&](size_t bytes) {
        void* p = ws + off;
        off = (off + bytes + 255) & ~(size_t)255;
        return p;
    };
    float*          proto   = (float*)carve(NCLS * DD * 4);
    float*          pn      = (float*)carve(NCLS * DD * 4);
    float*          selfs   = (float*)carve(NCLS * 4);
    float*          qInv    = (float*)carve(NQ * 4);
    float*          pre_max = (float*)carve(NQ * 4);
    int*            pre_lab = (int*)carve(NQ * 4);
    float*          apn     = (float*)carve(NCLS * DD * 4);
    unsigned short* xh      = (unsigned short*)carve((size_t)NQ * DD * 2);
    int*            topi4   = (int*)carve((size_t)NQ * CAND * 4);
    float*          topv    = (float*)carve((size_t)NQ * KNB * 4);
    int*            topi    = (int*)carve((size_t)NQ * KNB * 4);
    float*          scoreb  = (float*)carve((size_t)NQ * CAND * 4);
    if (off > ws_size) return;

    proto_kernel<<<NCLS, 256, 0, stream>>>(x, proto, pn, selfs);
    presim_kernel<<<NQ, 256, 0, stream>>>(x, pn, xh, qInv, pre_max, pre_lab);
    adapt_proto_kernel<<<NCLS, 256, 0, stream>>>(x, proto, selfs, pre_max, pre_lab, apn);
    simtopk_kernel<<<NQ / 128 * NCH, 256, 0, stream>>>(xh, topi4);
    rescore_kernel<<<NQ * 4, 64, 0, stream>>>(x, qInv, topi4, scoreb);
    topk_kernel<<<NQ, 64, 0, stream>>>(scoreb, topi4, topv, topi);
    final_kernel<<<NQ, 256, 0, stream>>>(x, apn, topv, topi, tao, out);
}

// Round 8
// 404.724 us; speedup vs baseline: 1.0217x; 1.0217x over previous
//
#include <hip/hip_runtime.h>
#include <math.h>

#define NCLS 64
#define KS 5
#define DD 256
#define NQ 8192   // NCLS*128
#define KNB 10
#define QK 12     // per-chunk candidate list depth (need >=10 for exact containment)
#define NCH 8     // column chunks per row (1024 cols each)
#define CAND 96   // NCH * QK

typedef __attribute__((ext_vector_type(8))) short short8;   // 8 bf16 bit-patterns (4 VGPRs)
typedef __attribute__((ext_vector_type(4))) float f32x4;    // MFMA C/D frag

// row index in x (fp32 row units) of query g
__device__ __forceinline__ int qrow(int g) { return (g >> 7) * 133 + KS + (g & 127); }

__device__ __forceinline__ unsigned short bf16_rne(float f) {
    unsigned int u = __float_as_uint(f);
    u += 0x7fffu + ((u >> 16) & 1u);
    return (unsigned short)(u >> 16);
}

__device__ __forceinline__ float blk_reduce_sum(float v, float* red) {
    int t = threadIdx.x;
    red[t] = v; __syncthreads();
    for (int off = 128; off > 0; off >>= 1) {
        if (t < off) red[t] += red[t + off];
        __syncthreads();
    }
    float r = red[0];
    __syncthreads();
    return r;
}

__device__ __forceinline__ float blk_reduce_max(float v, float* red) {
    int t = threadIdx.x;
    red[t] = v; __syncthreads();
    for (int off = 128; off > 0; off >>= 1) {
        if (t < off) red[t] = fmaxf(red[t], red[t + off]);
        __syncthreads();
    }
    float r = red[0];
    __syncthreads();
    return r;
}

// ---------- K1: proto, pn, self_sim ----------
__global__ __launch_bounds__(256) void proto_kernel(const float* __restrict__ x,
                                                    float* proto, float* pn, float* selfs) {
    __shared__ float red[256];
    int c = blockIdx.x, t = threadIdx.x;
    float s = 0.f;
    for (int j = 0; j < KS; j++) s += x[(long)(c * 133 + j) * DD + t];
    float p = s / 5.0f;
    proto[c * DD + t] = p;
    float n2 = blk_reduce_sum(p * p, red);
    float pv = p / sqrtf(n2);
    pn[c * DD + t] = pv;
    float ss = blk_reduce_sum(pv * pv, red);
    if (t == 0) selfs[c] = ss;
}

// ---------- K2: FUSED split + pre_sim argmax per query ----------
__global__ __launch_bounds__(256) void presim_kernel(const float* __restrict__ x,
                                                     const float* __restrict__ pn,
                                                     unsigned short* __restrict__ xh,
                                                     float* __restrict__ qInv,
                                                     float* pre_max, int* pre_label) {
    __shared__ __align__(16) float qs[256];
    __shared__ float red[256];
    __shared__ float part[256];
    __shared__ float sims[64];
    int g = blockIdx.x, t = threadIdx.x;
    float v = x[(long)qrow(g) * DD + t];
    qs[t] = v;
    float n2 = blk_reduce_sum(v * v, red);   // barrier publishes qs too
    float inv = 1.f / sqrtf(n2);
    xh[g * DD + t] = bf16_rne(v * inv);
    if (t == 0) qInv[g] = inv;
    int c = t >> 2, tl = t & 3;
    float s = 0.f;
    const float4* qp = (const float4*)(qs + tl * 64);
    const float4* pp = (const float4*)(pn + c * DD + tl * 64);
    #pragma unroll
    for (int u4 = 0; u4 < 16; u4++) {
        float4 a = qp[u4], b = pp[u4];
        s += a.x * b.x; s += a.y * b.y; s += a.z * b.z; s += a.w * b.w;
    }
    part[t] = s; __syncthreads();
    if (tl == 0) sims[c] = part[t] + part[t + 1] + part[t + 2] + part[t + 3];
    __syncthreads();
    if (t == 0) {
        float best = sims[0]; int bi = 0;
        for (int c2 = 1; c2 < 64; c2++)
            if (sims[c2] > best) { best = sims[c2]; bi = c2; }
        pre_max[g] = best * inv;
        pre_label[g] = bi;
    }
}

// ---------- K3: adapted prototypes — LDS-compacted member list ----------
__global__ __launch_bounds__(256) void adapt_proto_kernel(const float* __restrict__ x,
                                                          const float* __restrict__ proto,
                                                          const float* __restrict__ selfs,
                                                          const float* __restrict__ pre_max,
                                                          const int* __restrict__ pre_label,
                                                          float* apn) {
    __shared__ int lst[NQ];
    __shared__ float red[256];
    __shared__ int cnt_s;
    int c = blockIdx.x, t = threadIdx.x;
    if (t == 0) cnt_s = 0;
    __syncthreads();
    float lm = -INFINITY;
    for (int g = t; g < NQ; g += 256) {
        if (pre_label[g] == c) {
            int p = atomicAdd(&cnt_s, 1);
            lst[p] = g;
            lm = fmaxf(lm, pre_max[g]);
        }
    }
    float m = fmaxf(blk_reduce_max(lm, red), selfs[c]);   // barrier publishes lst/cnt_s
    int cnt = cnt_s;
    float ls = 0.f;
    for (int e = t; e < cnt; e += 256) ls += expf(pre_max[lst[e]] - m);
    float es = expf(selfs[c] - m);
    float Z = blk_reduce_sum(ls, red) + es;
    float a0 = es * proto[c * DD + t], a1 = 0.f, a2 = 0.f, a3 = 0.f;
    int e = 0;
    for (; e + 3 < cnt; e += 4) {
        int g0 = lst[e], g1 = lst[e + 1], g2 = lst[e + 2], g3 = lst[e + 3];
        float w0 = expf(pre_max[g0] - m), w1 = expf(pre_max[g1] - m);
        float w2 = expf(pre_max[g2] - m), w3 = expf(pre_max[g3] - m);
        a0 += w0 * x[(long)qrow(g0) * DD + t];
        a1 += w1 * x[(long)qrow(g1) * DD + t];
        a2 += w2 * x[(long)qrow(g2) * DD + t];
        a3 += w3 * x[(long)qrow(g3) * DD + t];
    }
    for (; e < cnt; e++) {
        int g0 = lst[e];
        a0 += expf(pre_max[g0] - m) * x[(long)qrow(g0) * DD + t];
    }
    float ap = ((a0 + a1) + (a2 + a3)) / Z;
    float n2 = blk_reduce_sum(ap * ap, red);
    apn[c * DD + t] = ap / sqrtf(n2);
}

// ---------- K4: bf16 MFMA coarse cosines — branchless min/max scan ----------
// R7 counters: scan VALU-bound (~600 VALU/tile vs 16 MFMA; VALUBusy 59%).
// (1) Sorted bubble insert via umax/umin pairs: 2 ops/step, NO guard branch
//     (sub-threshold keys bubble off the end — bit-identical result).
// (2) acc init = 2.0f -> scores in [1,3], strictly positive, u32-monotone:
//     pack = AND+OR (2 ops), no sign-fold.
// (3) Tri-buffer staging: ONE barrier/tile (write t+2 only needs t-1's reads,
//     which the previous barrier ordered). 24KB tiles + dump alias = 26.6KB.
#define INSERT_KEY(KEYS, KEY)                                                      \
    {                                                                              \
        unsigned int ck = (KEY);                                                   \
        _Pragma("unroll")                                                          \
        for (int p = 0; p < QK; ++p) {                                             \
            unsigned int tmp = KEYS[p];                                            \
            KEYS[p] = tmp > ck ? tmp : ck;   /* v_max_u32 */                       \
            ck = tmp > ck ? ck : tmp;        /* v_min_u32 */                       \
        }                                                                          \
    }

#define COMPUTE_TILE_L(LBUF, TILE)                                                 \
    {                                                                              \
        f32x4 acc0 = {2.f, 2.f, 2.f, 2.f};                                         \
        f32x4 acc1 = {2.f, 2.f, 2.f, 2.f};                                         \
        _Pragma("unroll")                                                          \
        for (int kc = 0; kc < 8; kc++) {                                           \
            short8 cf = *(const short8*)((LBUF) + ((nn << 8) + (((kc * 4 + qd) ^ xm) << 3))); \
            acc0 = __builtin_amdgcn_mfma_f32_16x16x32_bf16(cf, qh0[kc], acc0, 0, 0, 0); \
            acc1 = __builtin_amdgcn_mfma_f32_16x16x32_bf16(cf, qh1[kc], acc1, 0, 0, 0); \
        }                                                                          \
        _Pragma("unroll")                                                          \
        for (int r = 0; r < 4; ++r) {                                              \
            unsigned int cid = (unsigned int)((TILE) * 16 + 4 * qd + r);           \
            unsigned int k0 = (__float_as_uint(acc0[r]) & 0xFFFFFC00u) | cid;      \
            INSERT_KEY(keys0, k0)                                                  \
            unsigned int k1 = (__float_as_uint(acc1[r]) & 0xFFFFFC00u) | cid;      \
            INSERT_KEY(keys1, k1)                                                  \
        }                                                                          \
    }

#define GLOAD(RA, RB, TL)                                                          \
    {                                                                              \
        const unsigned short* tb = xh + ((size_t)(col0 + (TL) * 16) << 8);         \
        RA = *(const uint4*)(tb + (G0 << 3));                                      \
        RB = *(const uint4*)(tb + (G1 << 3));                                      \
    }

#define DSWRITE(P, RA, RB)                                                         \
    {                                                                              \
        *(uint4*)((P) + (u0 << 3)) = RA;                                           \
        *(uint4*)((P) + (u1 << 3)) = RB;                                           \
    }

__global__ __launch_bounds__(256, 2) void simtopk_kernel(const unsigned short* __restrict__ xh,
                                                         int* __restrict__ topi4) {
    __shared__ uint4 smem4[1664];   // 26.6 KB: tri-buffer tiles [0,24KB); dump alias
    unsigned short* Tb = (unsigned short*)smem4;

    const int t = threadIdx.x;
    const int b = blockIdx.x;
    const int rb = b >> 3;          // 64 row-blocks of 128 rows
    const int ch = b & 7;           // column chunk (== XCD id under round-robin: L2-local)
    const int row0 = rb * 128;
    const int col0 = ch * 1024;

    const int wv = t >> 6;
    const int lane = t & 63;
    const int qd = lane >> 4;
    const int nn = lane & 15;
    const int xm = nn & 7;

    // staging geometry: tile = 512 x 16B units; thread handles G0=t, G1=256+t
    const int G0 = t, G1 = 256 + t;
    const int r0r = G0 >> 5, c0u = G0 & 31;
    const int u0 = r0r * 32 + (c0u ^ (r0r & 7));
    const int r1r = G1 >> 5, c1u = G1 & 31;
    const int u1 = r1r * 32 + (c1u ^ (r1r & 7));

    // TWO query groups per wave (rows wv*32+nn and wv*32+16+nn)
    const int arow0 = (row0 + wv * 32 + nn) * DD;
    const int arow1 = (row0 + wv * 32 + 16 + nn) * DD;
    short8 qh0[8], qh1[8];
    #pragma unroll
    for (int kc = 0; kc < 8; kc++) {
        qh0[kc] = *(const short8*)(xh + arow0 + kc * 32 + qd * 8);
        qh1[kc] = *(const short8*)(xh + arow1 + kc * 32 + qd * 8);
    }

    unsigned int keys0[QK], keys1[QK];
    #pragma unroll
    for (int s = 0; s < QK; s++) { keys0[s] = 0u; keys1[s] = 0u; }

    uint4 RA, RB;
    GLOAD(RA, RB, 0)
    DSWRITE(Tb, RA, RB)
    GLOAD(RA, RB, 1)
    DSWRITE(Tb + 4096, RA, RB)
    __syncthreads();                         // tiles 0,1 ready

    int roff = 0, woff = 8192;               // read / write buffer offsets (shorts)
    #pragma unroll 1
    for (int t2 = 0; t2 < 64; ++t2) {
        if (t2 < 62) GLOAD(RA, RB, t2 + 2)   // issue early (hides under compute)
        COMPUTE_TILE_L(Tb + roff, t2)
        if (t2 < 62) DSWRITE(Tb + woff, RA, RB)
        __syncthreads();                     // publishes tile t2+2; orders reads of t2
        roff = (roff == 8192) ? 0 : roff + 4096;
        woff = (woff == 8192) ? 0 : woff + 4096;
    }

    // dump both groups (wave-private regions; in-order DS, no barrier), then
    // 32 lanes merge: lanes 0..15 group0 queries, lanes 16..31 group1.
    unsigned int* dw = (unsigned int*)smem4 + wv * 1664;
    #pragma unroll
    for (int s = 0; s < QK; s++) dw[lane * 13 + s] = keys0[s];
    unsigned int* dw1 = dw + 832;
    #pragma unroll
    for (int s = 0; s < QK; s++) dw1[lane * 13 + s] = keys1[s];
    if (lane < 32) {
        const int grp = lane >> 4;
        const int qq = lane & 15;
        unsigned int* dm = dw + grp * 832;
        const int g = row0 + wv * 32 + grp * 16 + qq;
        const int b0 = (qq +  0) * 13;
        const int b1 = (qq + 16) * 13;
        const int b2 = (qq + 32) * 13;
        const int b3 = (qq + 48) * 13;
        int p0 = 0, p1 = 0, p2 = 0, p3 = 0;
        for (int s = 0; s < QK; s++) {
            unsigned int v0 = (p0 < QK) ? dm[b0 + p0] : 0u;
            unsigned int v1 = (p1 < QK) ? dm[b1 + p1] : 0u;
            unsigned int v2 = (p2 < QK) ? dm[b2 + p2] : 0u;
            unsigned int v3 = (p3 < QK) ? dm[b3 + p3] : 0u;
            unsigned int bv = v0; int bw = 0;
            if (v1 > bv) { bv = v1; bw = 1; }
            if (v2 > bv) { bv = v2; bw = 2; }
            if (v3 > bv) { bv = v3; bw = 3; }
            topi4[g * CAND + ch * QK + s] = col0 + (int)(bv & 1023u);
            if (bw == 0) p0++; else if (bw == 1) p1++; else if (bw == 2) p2++; else p3++;
        }
    }
}

// ---------- K5: FUSED exact fp32 rescoring + wave-parallel top-10 ----------
// One block (4 waves) per query: waves score 24 candidates each into LDS
// (same 8-deep ILP gather structure as R6), barrier, wave 0 runs the 64-lane
// shuffle-argmax top-10. Kills the topk launch + 6MB scoreb HBM round-trip.
__global__ __launch_bounds__(256, 4) void rescore_kernel(const float* __restrict__ x,
                                                         const float* __restrict__ qInv,
                                                         const int* __restrict__ topi4,
                                                         float* __restrict__ topv,
                                                         int* __restrict__ topi) {
    __shared__ float sc[CAND];
    __shared__ int   si[CAND];
    const int g = blockIdx.x;
    const int t = threadIdx.x;
    const int lane = t & 63;
    const int w = t >> 6;            // wave's candidate group [24w, 24w+24)
    const float4 a4 = *(const float4*)(x + (long)qrow(g) * DD + lane * 4);
    const float qg = qInv[g];
    const int cb = g * CAND + w * 24;
    #pragma unroll 1
    for (int r = 0; r < 3; ++r) {
        const int c0 = cb + r * 8;
        int jj[8];
        #pragma unroll
        for (int u = 0; u < 8; u++) {
            int j = topi4[c0 + u];
            jj[u] = __builtin_amdgcn_readfirstlane(((unsigned)j < NQ) ? j : 0);
        }
        float4 b[8];
        #pragma unroll
        for (int u = 0; u < 8; u++)
            b[u] = *(const float4*)(x + (long)qrow(jj[u]) * DD + lane * 4);
        float p[8];
        #pragma unroll
        for (int u = 0; u < 8; u++)
            p[u] = a4.x * b[u].x + a4.y * b[u].y + a4.z * b[u].z + a4.w * b[u].w;
        #pragma unroll
        for (int off = 32; off > 0; off >>= 1) {
            #pragma unroll
            for (int u = 0; u < 8; u++) p[u] += __shfl_xor(p[u], off);
        }
        if (lane == 0) {
            const int cl = w * 24 + r * 8;
            #pragma unroll
            for (int u = 0; u < 8; u++) { sc[cl + u] = p[u] * qInv[jj[u]] * qg; si[cl + u] = jj[u]; }
        }
    }
    __syncthreads();
    if (t < 64) {
        float v0 = sc[lane];
        int   i0 = si[lane];
        float v1 = -INFINITY; int i1 = 0x7fffffff;
        if (lane < CAND - 64) { v1 = sc[64 + lane]; i1 = si[64 + lane]; }
        #pragma unroll 1
        for (int s = 0; s < KNB; ++s) {
            bool sel1 = (v1 > v0) || (v1 == v0 && i1 < i0);
            float bv = sel1 ? v1 : v0;
            int   bi = sel1 ? i1 : i0;
            #pragma unroll
            for (int off = 32; off > 0; off >>= 1) {
                float ov = __shfl_xor(bv, off);
                int   oi = __shfl_xor(bi, off);
                bool take = (ov > bv) || (ov == bv && oi < bi);
                bv = take ? ov : bv;
                bi = take ? oi : bi;
            }
            if (lane == 0) { topv[g * KNB + s] = bv; topi[g * KNB + s] = bi; }
            if (i0 == bi) v0 = -INFINITY;
            if (i1 == bi) v1 = -INFINITY;
        }
    }
}

// ---------- K6: mutual-kNN softmax, adapted query, final cos sims ----------
__global__ __launch_bounds__(256) void final_kernel(const float* __restrict__ x,
                                                    const float* __restrict__ apn,
                                                    const float* __restrict__ topv,
                                                    const int* __restrict__ topi,
                                                    const float* __restrict__ tao_raw,
                                                    float* out) {
    __shared__ float tv[KNB]; __shared__ int ti[KNB]; __shared__ float w[KNB];
    __shared__ __align__(16) float aq[256]; __shared__ float red[256];
    int i = blockIdx.x, t = threadIdx.x;
    if (t < KNB) {
        tv[t] = topv[i * KNB + t];
        int j = topi[i * KNB + t];
        ti[t] = ((unsigned)j < NQ) ? j : 0;
    }
    __syncthreads();
    if (t < KNB) {
        int j = ti[t];
        bool mut = false;
        for (int s = 0; s < KNB; s++) mut = mut || (topi[j * KNB + s] == i);
        w[t] = mut ? tv[t] : -INFINITY;
    }
    __syncthreads();
    if (t == 0) {
        float m = -INFINITY;
        for (int s = 0; s < KNB; s++) m = fmaxf(m, w[s]);
        float e[KNB]; float Z = 0.f;
        for (int s = 0; s < KNB; s++) { e[s] = expf(w[s] - m); Z += e[s]; }
        for (int s = 0; s < KNB; s++) w[s] = e[s] / Z;
    }
    __syncthreads();
    float a = 0.f;
    for (int s = 0; s < KNB; s++) {
        float ws = w[s];
        if (ws != 0.f) a += ws * x[(long)qrow(ti[s]) * DD + t];
    }
    aq[t] = a;
    float n2 = blk_reduce_sum(a * a, red);
    float inv = 1.f / sqrtf(n2);
    int c = t >> 2, tl = t & 3;
    float sdot = 0.f;
    const float4* ap4 = (const float4*)(apn + c * DD + tl * 64);
    const float4* aq4 = (const float4*)(aq + tl * 64);
    #pragma unroll
    for (int u4 = 0; u4 < 16; u4++) {
        float4 av = aq4[u4], pv = ap4[u4];
        sdot += av.x * pv.x; sdot += av.y * pv.y; sdot += av.z * pv.z; sdot += av.w * pv.w;
    }
    red[t] = sdot; __syncthreads();
    if (tl == 0) {
        float sv = red[t] + red[t + 1] + red[t + 2] + red[t + 3];
        out[i * NCLS + c] = tao_raw[0] * sv * inv;
    }
}

extern "C" void kernel_launch(void* const* d_in, const int* in_sizes, int n_in,
                              void* d_out, int out_size, void* d_ws, size_t ws_size,
                              hipStream_t stream) {
    (void)in_sizes; (void)n_in; (void)out_size;
    const float* x   = (const float*)d_in[0];
    const float* tao = (const float*)d_in[1];
    float* out = (float*)d_out;

    char* ws = (char*)d_ws;
    size_t off = 0;
    auto carve = [&](size_t bytes) {
        void* p = ws + off;
        off = (off + bytes + 255) & ~(size_t)255;
        return p;
    };
    float*          proto   = (float*)carve(NCLS * DD * 4);
    float*          pn      = (float*)carve(NCLS * DD * 4);
    float*          selfs   = (float*)carve(NCLS * 4);
    float*          qInv    = (float*)carve(NQ * 4);
    float*          pre_max = (float*)carve(NQ * 4);
    int*            pre_lab = (int*)carve(NQ * 4);
    float*          apn     = (float*)carve(NCLS * DD * 4);
    unsigned short* xh      = (unsigned short*)carve((size_t)NQ * DD * 2);
    int*            topi4   = (int*)carve((size_t)NQ * CAND * 4);
    float*          topv    = (float*)carve((size_t)NQ * KNB * 4);
    int*            topi    = (int*)carve((size_t)NQ * KNB * 4);
    if (off > ws_size) return;

    proto_kernel<<<NCLS, 256, 0, stream>>>(x, proto, pn, selfs);
    presim_kernel<<<NQ, 256, 0, stream>>>(x, pn, xh, qInv, pre_max, pre_lab);
    adapt_proto_kernel<<<NCLS, 256, 0, stream>>>(x, proto, selfs, pre_max, pre_lab, apn);
    simtopk_kernel<<<NQ / 128 * NCH, 256, 0, stream>>>(xh, topi4);
    rescore_kernel<<<NQ, 256, 0, stream>>>(x, qInv, topi4, topv, topi);
    final_kernel<<<NQ, 256, 0, stream>>>(x, apn, topv, topi, tao, out);
}

// Round 9
// 403.942 us; speedup vs baseline: 1.0237x; 1.0019x over previous
//
#include <hip/hip_runtime.h>
#include <math.h>

#define NCLS 64
#define KS 5
#define DD 256
#define NQ 8192   // NCLS*128
#define KNB 10
#define QK 12     // per-chunk candidate list depth (need >=10 for exact containment)
#define NCH 8     // column chunks per row (1024 cols each)
#define CAND 96   // NCH * QK

typedef __attribute__((ext_vector_type(8))) short short8;   // 8 bf16 bit-patterns (4 VGPRs)
typedef __attribute__((ext_vector_type(4))) float f32x4;    // MFMA C/D frag

// row index in x (fp32 row units) of query g
__device__ __forceinline__ int qrow(int g) { return (g >> 7) * 133 + KS + (g & 127); }

__device__ __forceinline__ unsigned short bf16_rne(float f) {
    unsigned int u = __float_as_uint(f);
    u += 0x7fffu + ((u >> 16) & 1u);
    return (unsigned short)(u >> 16);
}

__device__ __forceinline__ float blk_reduce_sum(float v, float* red) {
    int t = threadIdx.x;
    red[t] = v; __syncthreads();
    for (int off = 128; off > 0; off >>= 1) {
        if (t < off) red[t] += red[t + off];
        __syncthreads();
    }
    float r = red[0];
    __syncthreads();
    return r;
}

__device__ __forceinline__ float blk_reduce_max(float v, float* red) {
    int t = threadIdx.x;
    red[t] = v; __syncthreads();
    for (int off = 128; off > 0; off >>= 1) {
        if (t < off) red[t] = fmaxf(red[t], red[t + off]);
        __syncthreads();
    }
    float r = red[0];
    __syncthreads();
    return r;
}

// ---------- K1: proto, pn, self_sim ----------
__global__ __launch_bounds__(256) void proto_kernel(const float* __restrict__ x,
                                                    float* proto, float* pn, float* selfs) {
    __shared__ float red[256];
    int c = blockIdx.x, t = threadIdx.x;
    float s = 0.f;
    for (int j = 0; j < KS; j++) s += x[(long)(c * 133 + j) * DD + t];
    float p = s / 5.0f;
    proto[c * DD + t] = p;
    float n2 = blk_reduce_sum(p * p, red);
    float pv = p / sqrtf(n2);
    pn[c * DD + t] = pv;
    float ss = blk_reduce_sum(pv * pv, red);
    if (t == 0) selfs[c] = ss;
}

// ---------- K2: FUSED split + pre_sim argmax — low-barrier version ----------
// R8: ~13 barriers/block (tree reduce) + 4-way LDS conflict on the quarter
// read (tl*64 = 0 mod 32 banks). Fix: 2-level reduce (wave shfl + red4 + ONE
// barrier), +4/64 padded qs2 (read base tl*68: banks tl*4+u*4, conflict-free;
// 272B stride keeps 16B alignment), wave-parallel argmax (lowest-index ties).
__global__ __launch_bounds__(256) void presim_kernel(const float* __restrict__ x,
                                                     const float* __restrict__ pn,
                                                     unsigned short* __restrict__ xh,
                                                     float* __restrict__ qInv,
                                                     float* pre_max, int* pre_label) {
    __shared__ __align__(16) float qs2[272];
    __shared__ float red4[4];
    __shared__ float part[256];
    __shared__ float sims[64];
    int g = blockIdx.x, t = threadIdx.x;
    const int lane = t & 63, wv = t >> 6;
    float v = x[(long)qrow(g) * DD + t];
    qs2[t + (t >> 6) * 4] = v;
    float v2 = v * v;
    #pragma unroll
    for (int off = 32; off > 0; off >>= 1) v2 += __shfl_xor(v2, off);
    if (lane == 0) red4[wv] = v2;
    __syncthreads();                               // publishes qs2 + red4
    float n2 = red4[0] + red4[1] + red4[2] + red4[3];
    float inv = 1.f / sqrtf(n2);
    xh[g * DD + t] = bf16_rne(v * inv);
    if (t == 0) qInv[g] = inv;
    int c = t >> 2, tl = t & 3;
    float s = 0.f;
    const float* qb = qs2 + tl * 68;
    const float4* pp = (const float4*)(pn + c * DD + tl * 64);
    #pragma unroll
    for (int u4 = 0; u4 < 16; u4++) {
        float4 a = *(const float4*)(qb + u4 * 4);
        float4 b = pp[u4];
        s += a.x * b.x; s += a.y * b.y; s += a.z * b.z; s += a.w * b.w;
    }
    part[t] = s; __syncthreads();
    if (tl == 0) sims[c] = part[t] + part[t + 1] + part[t + 2] + part[t + 3];
    __syncthreads();
    if (t < 64) {
        float bv = sims[t]; int bi = t;
        #pragma unroll
        for (int off = 32; off > 0; off >>= 1) {
            float ov = __shfl_xor(bv, off);
            int   oi = __shfl_xor(bi, off);
            bool take = (ov > bv) || (ov == bv && oi < bi);
            bv = take ? ov : bv;
            bi = take ? oi : bi;
        }
        if (t == 0) { pre_max[g] = bv * inv; pre_label[g] = bi; }
    }
}

// ---------- K3: adapted prototypes — LDS-compacted member list ----------
__global__ __launch_bounds__(256) void adapt_proto_kernel(const float* __restrict__ x,
                                                          const float* __restrict__ proto,
                                                          const float* __restrict__ selfs,
                                                          const float* __restrict__ pre_max,
                                                          const int* __restrict__ pre_label,
                                                          float* apn) {
    __shared__ int lst[NQ];
    __shared__ float red[256];
    __shared__ int cnt_s;
    int c = blockIdx.x, t = threadIdx.x;
    if (t == 0) cnt_s = 0;
    __syncthreads();
    float lm = -INFINITY;
    for (int g = t; g < NQ; g += 256) {
        if (pre_label[g] == c) {
            int p = atomicAdd(&cnt_s, 1);
            lst[p] = g;
            lm = fmaxf(lm, pre_max[g]);
        }
    }
    float m = fmaxf(blk_reduce_max(lm, red), selfs[c]);   // barrier publishes lst/cnt_s
    int cnt = cnt_s;
    float ls = 0.f;
    for (int e = t; e < cnt; e += 256) ls += expf(pre_max[lst[e]] - m);
    float es = expf(selfs[c] - m);
    float Z = blk_reduce_sum(ls, red) + es;
    float a0 = es * proto[c * DD + t], a1 = 0.f, a2 = 0.f, a3 = 0.f;
    int e = 0;
    for (; e + 3 < cnt; e += 4) {
        int g0 = lst[e], g1 = lst[e + 1], g2 = lst[e + 2], g3 = lst[e + 3];
        float w0 = expf(pre_max[g0] - m), w1 = expf(pre_max[g1] - m);
        float w2 = expf(pre_max[g2] - m), w3 = expf(pre_max[g3] - m);
        a0 += w0 * x[(long)qrow(g0) * DD + t];
        a1 += w1 * x[(long)qrow(g1) * DD + t];
        a2 += w2 * x[(long)qrow(g2) * DD + t];
        a3 += w3 * x[(long)qrow(g3) * DD + t];
    }
    for (; e < cnt; e++) {
        int g0 = lst[e];
        a0 += expf(pre_max[g0] - m) * x[(long)qrow(g0) * DD + t];
    }
    float ap = ((a0 + a1) + (a2 + a3)) / Z;
    float n2 = blk_reduce_sum(ap * ap, red);
    apn[c * DD + t] = ap / sqrtf(n2);
}

// ---------- K4: bf16 MFMA coarse cosines — 4 blocks/CU double-buffer ----------
// R8: occupancy 17.7% (2 blocks/CU; LDS 26.6KB from dumping BOTH groups at
// once). Fix: sequential per-group dump/merge (wave-private in-order DS, no
// barrier) -> 13.3KB, tiles double-buffered 2x8KB with 1 barrier/tile (the
// GLOAD->DSWRITE wait hides under ~400cyc of compute) -> 16KB total ->
// __launch_bounds__(256,4) = 4 blocks/CU = 16 waves (2x), VALU gaps filled.
#define INSERT_KEY(KEYS, KEY)                                                      \
    {                                                                              \
        unsigned int ck = (KEY);                                                   \
        _Pragma("unroll")                                                          \
        for (int p = 0; p < QK; ++p) {                                             \
            unsigned int tmp = KEYS[p];                                            \
            KEYS[p] = tmp > ck ? tmp : ck;   /* v_max_u32 */                       \
            ck = tmp > ck ? ck : tmp;        /* v_min_u32 */                       \
        }                                                                          \
    }

#define COMPUTE_TILE_L(LBUF, TILE)                                                 \
    {                                                                              \
        f32x4 acc0 = {2.f, 2.f, 2.f, 2.f};                                         \
        f32x4 acc1 = {2.f, 2.f, 2.f, 2.f};                                         \
        _Pragma("unroll")                                                          \
        for (int kc = 0; kc < 8; kc++) {                                           \
            short8 cf = *(const short8*)((LBUF) + ((nn << 8) + (((kc * 4 + qd) ^ xm) << 3))); \
            acc0 = __builtin_amdgcn_mfma_f32_16x16x32_bf16(cf, qh0[kc], acc0, 0, 0, 0); \
            acc1 = __builtin_amdgcn_mfma_f32_16x16x32_bf16(cf, qh1[kc], acc1, 0, 0, 0); \
        }                                                                          \
        _Pragma("unroll")                                                          \
        for (int r = 0; r < 4; ++r) {                                              \
            unsigned int cid = (unsigned int)((TILE) * 16 + 4 * qd + r);           \
            unsigned int k0 = (__float_as_uint(acc0[r]) & 0xFFFFFC00u) | cid;      \
            INSERT_KEY(keys0, k0)                                                  \
            unsigned int k1 = (__float_as_uint(acc1[r]) & 0xFFFFFC00u) | cid;      \
            INSERT_KEY(keys1, k1)                                                  \
        }                                                                          \
    }

#define GLOAD(RA, RB, TL)                                                          \
    {                                                                              \
        const unsigned short* tb = xh + ((size_t)(col0 + (TL) * 16) << 8);         \
        RA = *(const uint4*)(tb + (G0 << 3));                                      \
        RB = *(const uint4*)(tb + (G1 << 3));                                      \
    }

#define DSWRITE(P, RA, RB)                                                         \
    {                                                                              \
        *(uint4*)((P) + (u0 << 3)) = RA;                                           \
        *(uint4*)((P) + (u1 << 3)) = RB;                                           \
    }

// dump one group's keys into the wave-private region and merge (lanes 0..15)
#define DUMPMERGE(KEYS, GBASE)                                                     \
    {                                                                              \
        _Pragma("unroll")                                                          \
        for (int s = 0; s < QK; s++) dw[lane * 13 + s] = KEYS[s];                  \
        if (lane < 16) {                                                           \
            const int g = (GBASE) + lane;                                          \
            const int b0 = (lane +  0) * 13;                                       \
            const int b1 = (lane + 16) * 13;                                       \
            const int b2 = (lane + 32) * 13;                                       \
            const int b3 = (lane + 48) * 13;                                       \
            int p0 = 0, p1 = 0, p2 = 0, p3 = 0;                                    \
            for (int s = 0; s < QK; s++) {                                         \
                unsigned int v0 = (p0 < QK) ? dw[b0 + p0] : 0u;                    \
                unsigned int v1 = (p1 < QK) ? dw[b1 + p1] : 0u;                    \
                unsigned int v2 = (p2 < QK) ? dw[b2 + p2] : 0u;                    \
                unsigned int v3 = (p3 < QK) ? dw[b3 + p3] : 0u;                    \
                unsigned int bv = v0; int bw = 0;                                  \
                if (v1 > bv) { bv = v1; bw = 1; }                                  \
                if (v2 > bv) { bv = v2; bw = 2; }                                  \
                if (v3 > bv) { bv = v3; bw = 3; }                                  \
                topi4[g * CAND + ch * QK + s] = col0 + (int)(bv & 1023u);          \
                if (bw == 0) p0++; else if (bw == 1) p1++;                         \
                else if (bw == 2) p2++; else p3++;                                 \
            }                                                                      \
        }                                                                          \
    }

__global__ __launch_bounds__(256, 4) void simtopk_kernel(const unsigned short* __restrict__ xh,
                                                         int* __restrict__ topi4) {
    __shared__ uint4 smem4[1024];   // 16 KB: 2x8KB tile double-buffer; dump alias 13.3KB
    unsigned short* Tb = (unsigned short*)smem4;

    const int t = threadIdx.x;
    const int b = blockIdx.x;
    const int rb = b >> 3;          // 64 row-blocks of 128 rows
    const int ch = b & 7;           // column chunk (== XCD id under round-robin: L2-local)
    const int row0 = rb * 128;
    const int col0 = ch * 1024;

    const int wv = t >> 6;
    const int lane = t & 63;
    const int qd = lane >> 4;
    const int nn = lane & 15;
    const int xm = nn & 7;

    // staging geometry: tile = 512 x 16B units; thread handles G0=t, G1=256+t
    const int G0 = t, G1 = 256 + t;
    const int r0r = G0 >> 5, c0u = G0 & 31;
    const int u0 = r0r * 32 + (c0u ^ (r0r & 7));
    const int r1r = G1 >> 5, c1u = G1 & 31;
    const int u1 = r1r * 32 + (c1u ^ (r1r & 7));

    // TWO query groups per wave (rows wv*32+nn and wv*32+16+nn)
    const int arow0 = (row0 + wv * 32 + nn) * DD;
    const int arow1 = (row0 + wv * 32 + 16 + nn) * DD;
    short8 qh0[8], qh1[8];
    #pragma unroll
    for (int kc = 0; kc < 8; kc++) {
        qh0[kc] = *(const short8*)(xh + arow0 + kc * 32 + qd * 8);
        qh1[kc] = *(const short8*)(xh + arow1 + kc * 32 + qd * 8);
    }

    unsigned int keys0[QK], keys1[QK];
    #pragma unroll
    for (int s = 0; s < QK; s++) { keys0[s] = 0u; keys1[s] = 0u; }

    uint4 RA, RB;
    GLOAD(RA, RB, 0)
    DSWRITE(Tb, RA, RB)
    __syncthreads();                         // tile 0 ready in buffer 0

    #pragma unroll 1
    for (int t2 = 0; t2 < 64; ++t2) {
        const int cur = (t2 & 1) << 12;      // 0 / 4096 shorts (8KB buffers)
        if (t2 < 63) GLOAD(RA, RB, t2 + 1)   // issue early (hides under compute)
        COMPUTE_TILE_L(Tb + cur, t2)
        if (t2 < 63) DSWRITE(Tb + (cur ^ 4096), RA, RB)   // buffer last read pre-barrier
        __syncthreads();                     // publishes tile t2+1; orders reads of t2
    }

    // sequential per-group dump + merge: wave-private region, in-order DS.
    unsigned int* dw = (unsigned int*)smem4 + wv * 832;
    DUMPMERGE(keys0, row0 + wv * 32)
    DUMPMERGE(keys1, row0 + wv * 32 + 16)
}

// ---------- K5: FUSED exact fp32 rescoring + wave-parallel top-10 ----------
__global__ __launch_bounds__(256, 4) void rescore_kernel(const float* __restrict__ x,
                                                         const float* __restrict__ qInv,
                                                         const int* __restrict__ topi4,
                                                         float* __restrict__ topv,
                                                         int* __restrict__ topi) {
    __shared__ float sc[CAND];
    __shared__ int   si[CAND];
    const int g = blockIdx.x;
    const int t = threadIdx.x;
    const int lane = t & 63;
    const int w = t >> 6;            // wave's candidate group [24w, 24w+24)
    const float4 a4 = *(const float4*)(x + (long)qrow(g) * DD + lane * 4);
    const float qg = qInv[g];
    const int cb = g * CAND + w * 24;
    #pragma unroll 1
    for (int r = 0; r < 3; ++r) {
        const int c0 = cb + r * 8;
        int jj[8];
        #pragma unroll
        for (int u = 0; u < 8; u++) {
            int j = topi4[c0 + u];
            jj[u] = __builtin_amdgcn_readfirstlane(((unsigned)j < NQ) ? j : 0);
        }
        float4 b[8];
        #pragma unroll
        for (int u = 0; u < 8; u++)
            b[u] = *(const float4*)(x + (long)qrow(jj[u]) * DD + lane * 4);
        float p[8];
        #pragma unroll
        for (int u = 0; u < 8; u++)
            p[u] = a4.x * b[u].x + a4.y * b[u].y + a4.z * b[u].z + a4.w * b[u].w;
        #pragma unroll
        for (int off = 32; off > 0; off >>= 1) {
            #pragma unroll
            for (int u = 0; u < 8; u++) p[u] += __shfl_xor(p[u], off);
        }
        if (lane == 0) {
            const int cl = w * 24 + r * 8;
            #pragma unroll
            for (int u = 0; u < 8; u++) { sc[cl + u] = p[u] * qInv[jj[u]] * qg; si[cl + u] = jj[u]; }
        }
    }
    __syncthreads();
    if (t < 64) {
        float v0 = sc[lane];
        int   i0 = si[lane];
        float v1 = -INFINITY; int i1 = 0x7fffffff;
        if (lane < CAND - 64) { v1 = sc[64 + lane]; i1 = si[64 + lane]; }
        #pragma unroll 1
        for (int s = 0; s < KNB; ++s) {
            bool sel1 = (v1 > v0) || (v1 == v0 && i1 < i0);
            float bv = sel1 ? v1 : v0;
            int   bi = sel1 ? i1 : i0;
            #pragma unroll
            for (int off = 32; off > 0; off >>= 1) {
                float ov = __shfl_xor(bv, off);
                int   oi = __shfl_xor(bi, off);
                bool take = (ov > bv) || (ov == bv && oi < bi);
                bv = take ? ov : bv;
                bi = take ? oi : bi;
            }
            if (lane == 0) { topv[g * KNB + s] = bv; topi[g * KNB + s] = bi; }
            if (i0 == bi) v0 = -INFINITY;
            if (i1 == bi) v1 = -INFINITY;
        }
    }
}

// ---------- K6: mutual-kNN softmax, adapted query, final cos sims ----------
// R8 counters: 6.3M LDS bank conflicts (quarter read tl*64 = same bank
// cluster), ~25 barriers/block, serial t==0 softmax. Fix: padded aq2
// (+4/64, read base tl*68 -> banks tl*4+u*4, conflict-free, 272B stride is
// 16B-aligned), lanes<16 shfl softmax, 2-level n2 reduce -> ~5 barriers.
__global__ __launch_bounds__(256) void final_kernel(const float* __restrict__ x,
                                                    const float* __restrict__ apn,
                                                    const float* __restrict__ topv,
                                                    const int* __restrict__ topi,
                                                    const float* __restrict__ tao_raw,
                                                    float* out) {
    __shared__ float tv[KNB]; __shared__ int ti[KNB]; __shared__ float w[KNB];
    __shared__ __align__(16) float aq2[272];
    __shared__ float red4[4];
    __shared__ float part[256];
    int i = blockIdx.x, t = threadIdx.x;
    const int lane = t & 63, wv = t >> 6;
    if (t < KNB) {
        tv[t] = topv[i * KNB + t];
        int j = topi[i * KNB + t];
        ti[t] = ((unsigned)j < NQ) ? j : 0;
    }
    __syncthreads();
    if (t < KNB) {
        int j = ti[t];
        bool mut = false;
        for (int s = 0; s < KNB; s++) mut = mut || (topi[j * KNB + s] == i);
        w[t] = mut ? tv[t] : -INFINITY;
    }
    __syncthreads();
    if (t < 16) {                               // wave-parallel softmax (10 live)
        float val = (t < KNB) ? w[t] : -INFINITY;
        float m = val;
        #pragma unroll
        for (int off = 8; off > 0; off >>= 1) m = fmaxf(m, __shfl_xor(m, off));
        float e = (t < KNB) ? expf(val - m) : 0.f;
        float Z = e;
        #pragma unroll
        for (int off = 8; off > 0; off >>= 1) Z += __shfl_xor(Z, off);
        if (t < KNB) w[t] = e / Z;
    }
    __syncthreads();
    float a = 0.f;
    for (int s = 0; s < KNB; s++) {
        float ws = w[s];
        if (ws != 0.f) a += ws * x[(long)qrow(ti[s]) * DD + t];
    }
    aq2[t + (t >> 6) * 4] = a;
    float v2 = a * a;
    #pragma unroll
    for (int off = 32; off > 0; off >>= 1) v2 += __shfl_xor(v2, off);
    if (lane == 0) red4[wv] = v2;
    __syncthreads();                            // publishes aq2 + red4
    float n2 = red4[0] + red4[1] + red4[2] + red4[3];
    float inv = 1.f / sqrtf(n2);
    int c = t >> 2, tl = t & 3;
    float sdot = 0.f;
    const float* aqb = aq2 + tl * 68;
    const float4* ap4 = (const float4*)(apn + c * DD + tl * 64);
    #pragma unroll
    for (int u4 = 0; u4 < 16; u4++) {
        float4 av = *(const float4*)(aqb + u4 * 4);
        float4 pv = ap4[u4];
        sdot += av.x * pv.x; sdot += av.y * pv.y; sdot += av.z * pv.z; sdot += av.w * pv.w;
    }
    part[t] = sdot; __syncthreads();
    if (tl == 0) {
        float sv = part[t] + part[t + 1] + part[t + 2] + part[t + 3];
        out[i * NCLS + c] = tao_raw[0] * sv * inv;
    }
}

extern "C" void kernel_launch(void* const* d_in, const int* in_sizes, int n_in,
                              void* d_out, int out_size, void* d_ws, size_t ws_size,
                              hipStream_t stream) {
    (void)in_sizes; (void)n_in; (void)out_size;
    const float* x   = (const float*)d_in[0];
    const float* tao = (const float*)d_in[1];
    float* out = (float*)d_out;

    char* ws = (char*)d_ws;
    size_t off = 0;
    auto carve = [&](size_t bytes) {
        void* p = ws + off;
        off = (off + bytes + 255) & ~(size_t)255;
        return p;
    };
    float*          proto   = (float*)carve(NCLS * DD * 4);
    float*          pn      = (float*)carve(NCLS * DD * 4);
    float*          selfs   = (float*)carve(NCLS * 4);
    float*          qInv    = (float*)carve(NQ * 4);
    float*          pre_max = (float*)carve(NQ * 4);
    int*            pre_lab = (int*)carve(NQ * 4);
    float*          apn     = (float*)carve(NCLS * DD * 4);
    unsigned short* xh      = (unsigned short*)carve((size_t)NQ * DD * 2);
    int*            topi4   = (int*)carve((size_t)NQ * CAND * 4);
    float*          topv    = (float*)carve((size_t)NQ * KNB * 4);
    int*            topi    = (int*)carve((size_t)NQ * KNB * 4);
    if (off > ws_size) return;

    proto_kernel<<<NCLS, 256, 0, stream>>>(x, proto, pn, selfs);
    presim_kernel<<<NQ, 256, 0, stream>>>(x, pn, xh, qInv, pre_max, pre_lab);
    adapt_proto_kernel<<<NCLS, 256, 0, stream>>>(x, proto, selfs, pre_max, pre_lab, apn);
    simtopk_kernel<<<NQ / 128 * NCH, 256, 0, stream>>>(xh, topi4);
    rescore_kernel<<<NQ, 256, 0, stream>>>(x, qInv, topi4, topv, topi);
    final_kernel<<<NQ, 256, 0, stream>>>(x, apn, topv, topi, tao, out);
}

// Round 10
// 392.923 us; speedup vs baseline: 1.0524x; 1.0280x over previous
//
#include <hip/hip_runtime.h>
#include <math.h>

#define NCLS 64
#define KS 5
#define DD 256
#define NQ 8192   // NCLS*128
#define KNB 10
#define QK 12     // per-chunk candidate list depth (need >=10 for exact containment)
#define NCH 8     // column chunks per row (1024 cols each)
#define CAND 96   // NCH * QK

typedef __attribute__((ext_vector_type(8))) short short8;   // 8 bf16 bit-patterns (4 VGPRs)
typedef __attribute__((ext_vector_type(4))) float f32x4;    // MFMA C/D frag

// row index in x (fp32 row units) of query g
__device__ __forceinline__ int qrow(int g) { return (g >> 7) * 133 + KS + (g & 127); }

__device__ __forceinline__ unsigned short bf16_rne(float f) {
    unsigned int u = __float_as_uint(f);
    u += 0x7fffu + ((u >> 16) & 1u);
    return (unsigned short)(u >> 16);
}

__device__ __forceinline__ float blk_reduce_sum(float v, float* red) {
    int t = threadIdx.x;
    red[t] = v; __syncthreads();
    for (int off = 128; off > 0; off >>= 1) {
        if (t < off) red[t] += red[t + off];
        __syncthreads();
    }
    float r = red[0];
    __syncthreads();
    return r;
}

__device__ __forceinline__ float blk_reduce_max(float v, float* red) {
    int t = threadIdx.x;
    red[t] = v; __syncthreads();
    for (int off = 128; off > 0; off >>= 1) {
        if (t < off) red[t] = fmaxf(red[t], red[t + off]);
        __syncthreads();
    }
    float r = red[0];
    __syncthreads();
    return r;
}

// ---------- K1: proto, pn, self_sim ----------
__global__ __launch_bounds__(256) void proto_kernel(const float* __restrict__ x,
                                                    float* proto, float* pn, float* selfs) {
    __shared__ float red[256];
    int c = blockIdx.x, t = threadIdx.x;
    float s = 0.f;
    for (int j = 0; j < KS; j++) s += x[(long)(c * 133 + j) * DD + t];
    float p = s / 5.0f;
    proto[c * DD + t] = p;
    float n2 = blk_reduce_sum(p * p, red);
    float pv = p / sqrtf(n2);
    pn[c * DD + t] = pv;
    float ss = blk_reduce_sum(pv * pv, red);
    if (t == 0) selfs[c] = ss;
}

// ---------- K2: FUSED split + pre_sim argmax — low-barrier version ----------
__global__ __launch_bounds__(256) void presim_kernel(const float* __restrict__ x,
                                                     const float* __restrict__ pn,
                                                     unsigned short* __restrict__ xh,
                                                     float* __restrict__ qInv,
                                                     float* pre_max, int* pre_label) {
    __shared__ __align__(16) float qs2[272];
    __shared__ float red4[4];
    __shared__ float part[256];
    __shared__ float sims[64];
    int g = blockIdx.x, t = threadIdx.x;
    const int lane = t & 63, wv = t >> 6;
    float v = x[(long)qrow(g) * DD + t];
    qs2[t + (t >> 6) * 4] = v;
    float v2 = v * v;
    #pragma unroll
    for (int off = 32; off > 0; off >>= 1) v2 += __shfl_xor(v2, off);
    if (lane == 0) red4[wv] = v2;
    __syncthreads();                               // publishes qs2 + red4
    float n2 = red4[0] + red4[1] + red4[2] + red4[3];
    float inv = 1.f / sqrtf(n2);
    xh[g * DD + t] = bf16_rne(v * inv);
    if (t == 0) qInv[g] = inv;
    int c = t >> 2, tl = t & 3;
    float s = 0.f;
    const float* qb = qs2 + tl * 68;
    const float4* pp = (const float4*)(pn + c * DD + tl * 64);
    #pragma unroll
    for (int u4 = 0; u4 < 16; u4++) {
        float4 a = *(const float4*)(qb + u4 * 4);
        float4 b = pp[u4];
        s += a.x * b.x; s += a.y * b.y; s += a.z * b.z; s += a.w * b.w;
    }
    part[t] = s; __syncthreads();
    if (tl == 0) sims[c] = part[t] + part[t + 1] + part[t + 2] + part[t + 3];
    __syncthreads();
    if (t < 64) {
        float bv = sims[t]; int bi = t;
        #pragma unroll
        for (int off = 32; off > 0; off >>= 1) {
            float ov = __shfl_xor(bv, off);
            int   oi = __shfl_xor(bi, off);
            bool take = (ov > bv) || (ov == bv && oi < bi);
            bv = take ? ov : bv;
            bi = take ? oi : bi;
        }
        if (t == 0) { pre_max[g] = bv * inv; pre_label[g] = bi; }
    }
}

// ---------- K3: adapted prototypes — LDS-compacted member list ----------
__global__ __launch_bounds__(256) void adapt_proto_kernel(const float* __restrict__ x,
                                                          const float* __restrict__ proto,
                                                          const float* __restrict__ selfs,
                                                          const float* __restrict__ pre_max,
                                                          const int* __restrict__ pre_label,
                                                          float* apn) {
    __shared__ int lst[NQ];
    __shared__ float red[256];
    __shared__ int cnt_s;
    int c = blockIdx.x, t = threadIdx.x;
    if (t == 0) cnt_s = 0;
    __syncthreads();
    float lm = -INFINITY;
    for (int g = t; g < NQ; g += 256) {
        if (pre_label[g] == c) {
            int p = atomicAdd(&cnt_s, 1);
            lst[p] = g;
            lm = fmaxf(lm, pre_max[g]);
        }
    }
    float m = fmaxf(blk_reduce_max(lm, red), selfs[c]);   // barrier publishes lst/cnt_s
    int cnt = cnt_s;
    float ls = 0.f;
    for (int e = t; e < cnt; e += 256) ls += expf(pre_max[lst[e]] - m);
    float es = expf(selfs[c] - m);
    float Z = blk_reduce_sum(ls, red) + es;
    float a0 = es * proto[c * DD + t], a1 = 0.f, a2 = 0.f, a3 = 0.f;
    int e = 0;
    for (; e + 3 < cnt; e += 4) {
        int g0 = lst[e], g1 = lst[e + 1], g2 = lst[e + 2], g3 = lst[e + 3];
        float w0 = expf(pre_max[g0] - m), w1 = expf(pre_max[g1] - m);
        float w2 = expf(pre_max[g2] - m), w3 = expf(pre_max[g3] - m);
        a0 += w0 * x[(long)qrow(g0) * DD + t];
        a1 += w1 * x[(long)qrow(g1) * DD + t];
        a2 += w2 * x[(long)qrow(g2) * DD + t];
        a3 += w3 * x[(long)qrow(g3) * DD + t];
    }
    for (; e < cnt; e++) {
        int g0 = lst[e];
        a0 += expf(pre_max[g0] - m) * x[(long)qrow(g0) * DD + t];
    }
    float ap = ((a0 + a1) + (a2 + a3)) / Z;
    float n2 = blk_reduce_sum(ap * ap, red);
    apn[c * DD + t] = ap / sqrtf(n2);
}

// ---------- K4: bf16 MFMA coarse cosines — 16 q/wave, 16 waves/CU ----------
// R9 lesson: occupancy is GRID-bound, not LDS-bound. 32q/wave yields only
// 2048 waves = 8/CU; the scan's fixed ~22us chip-wide VALU issue then sits
// behind unhidden ds_read->MFMA->scan chains (dur 104us). Revert to 16q/wave
// (grid 128rb x 8ch = 1024 blocks = 4/CU = 16 waves/CU) KEEPING all wins:
// branchless minmax insert, acc=2.0 monotone pack, double-buffer 1
// barrier/tile, sequential dump, 16KB LDS, (256,4).
#define INSERT_KEY(KEYS, KEY)                                                      \
    {                                                                              \
        unsigned int ck = (KEY);                                                   \
        _Pragma("unroll")                                                          \
        for (int p = 0; p < QK; ++p) {                                             \
            unsigned int tmp = KEYS[p];                                            \
            KEYS[p] = tmp > ck ? tmp : ck;   /* v_max_u32 */                       \
            ck = tmp > ck ? ck : tmp;        /* v_min_u32 */                       \
        }                                                                          \
    }

#define COMPUTE_TILE_L(LBUF, TILE)                                                 \
    {                                                                              \
        f32x4 acc = {2.f, 2.f, 2.f, 2.f};                                          \
        _Pragma("unroll")                                                          \
        for (int kc = 0; kc < 8; kc++) {                                           \
            short8 cf = *(const short8*)((LBUF) + ((nn << 8) + (((kc * 4 + qd) ^ xm) << 3))); \
            acc = __builtin_amdgcn_mfma_f32_16x16x32_bf16(cf, qh[kc], acc, 0, 0, 0); \
        }                                                                          \
        _Pragma("unroll")                                                          \
        for (int r = 0; r < 4; ++r) {                                              \
            unsigned int cid = (unsigned int)((TILE) * 16 + 4 * qd + r);           \
            unsigned int k0 = (__float_as_uint(acc[r]) & 0xFFFFFC00u) | cid;       \
            INSERT_KEY(keys, k0)                                                   \
        }                                                                          \
    }

#define GLOAD(RA, RB, TL)                                                          \
    {                                                                              \
        const unsigned short* tb = xh + ((size_t)(col0 + (TL) * 16) << 8);         \
        RA = *(const uint4*)(tb + (G0 << 3));                                      \
        RB = *(const uint4*)(tb + (G1 << 3));                                      \
    }

#define DSWRITE(P, RA, RB)                                                         \
    {                                                                              \
        *(uint4*)((P) + (u0 << 3)) = RA;                                           \
        *(uint4*)((P) + (u1 << 3)) = RB;                                           \
    }

__global__ __launch_bounds__(256, 4) void simtopk_kernel(const unsigned short* __restrict__ xh,
                                                         int* __restrict__ topi4) {
    __shared__ uint4 smem4[1024];   // 16 KB: 2x8KB tile double-buffer; dump alias 13.3KB
    unsigned short* Tb = (unsigned short*)smem4;

    const int t = threadIdx.x;
    const int b = blockIdx.x;
    const int rb = b >> 3;          // 128 row-blocks of 64 rows
    const int ch = b & 7;           // column chunk (== XCD id under round-robin: L2-local)
    const int row0 = rb * 64;
    const int col0 = ch * 1024;

    const int wv = t >> 6;
    const int lane = t & 63;
    const int qd = lane >> 4;
    const int nn = lane & 15;
    const int xm = nn & 7;

    // staging geometry: tile = 512 x 16B units; thread handles G0=t, G1=256+t
    const int G0 = t, G1 = 256 + t;
    const int r0r = G0 >> 5, c0u = G0 & 31;
    const int u0 = r0r * 32 + (c0u ^ (r0r & 7));
    const int r1r = G1 >> 5, c1u = G1 & 31;
    const int u1 = r1r * 32 + (c1u ^ (r1r & 7));

    // Query fragments (MFMA B operand): lane holds Q[n=nn][k=kc*32+qd*8 ..+7]
    const int arow = (row0 + wv * 16 + nn) * DD;
    short8 qh[8];
    #pragma unroll
    for (int kc = 0; kc < 8; kc++)
        qh[kc] = *(const short8*)(xh + arow + kc * 32 + qd * 8);

    unsigned int keys[QK];
    #pragma unroll
    for (int s = 0; s < QK; s++) keys[s] = 0u;

    uint4 RA, RB;
    GLOAD(RA, RB, 0)
    DSWRITE(Tb, RA, RB)
    __syncthreads();                         // tile 0 ready in buffer 0

    #pragma unroll 1
    for (int t2 = 0; t2 < 64; ++t2) {
        const int cur = (t2 & 1) << 12;      // 0 / 4096 shorts (8KB buffers)
        if (t2 < 63) GLOAD(RA, RB, t2 + 1)   // issue early (hides under compute)
        COMPUTE_TILE_L(Tb + cur, t2)
        if (t2 < 63) DSWRITE(Tb + (cur ^ 4096), RA, RB)   // buffer last read pre-barrier
        __syncthreads();                     // publishes tile t2+1; orders reads of t2
    }

    // dump (wave-private region, in-order DS: no barrier) + 4-list merge.
    unsigned int* dw = (unsigned int*)smem4 + wv * 832;
    #pragma unroll
    for (int s = 0; s < QK; s++) dw[lane * 13 + s] = keys[s];
    if (lane < 16) {
        const int g = row0 + wv * 16 + lane;
        const int b0 = (lane +  0) * 13;
        const int b1 = (lane + 16) * 13;
        const int b2 = (lane + 32) * 13;
        const int b3 = (lane + 48) * 13;
        int p0 = 0, p1 = 0, p2 = 0, p3 = 0;
        for (int s = 0; s < QK; s++) {
            unsigned int v0 = (p0 < QK) ? dw[b0 + p0] : 0u;
            unsigned int v1 = (p1 < QK) ? dw[b1 + p1] : 0u;
            unsigned int v2 = (p2 < QK) ? dw[b2 + p2] : 0u;
            unsigned int v3 = (p3 < QK) ? dw[b3 + p3] : 0u;
            unsigned int bv = v0; int bw = 0;
            if (v1 > bv) { bv = v1; bw = 1; }
            if (v2 > bv) { bv = v2; bw = 2; }
            if (v3 > bv) { bv = v3; bw = 3; }
            topi4[g * CAND + ch * QK + s] = col0 + (int)(bv & 1023u);
            if (bw == 0) p0++; else if (bw == 1) p1++; else if (bw == 2) p2++; else p3++;
        }
    }
}

// ---------- K5: FUSED exact fp32 rescoring + wave-parallel top-10 ----------
__global__ __launch_bounds__(256, 4) void rescore_kernel(const float* __restrict__ x,
                                                         const float* __restrict__ qInv,
                                                         const int* __restrict__ topi4,
                                                         float* __restrict__ topv,
                                                         int* __restrict__ topi) {
    __shared__ float sc[CAND];
    __shared__ int   si[CAND];
    const int g = blockIdx.x;
    const int t = threadIdx.x;
    const int lane = t & 63;
    const int w = t >> 6;            // wave's candidate group [24w, 24w+24)
    const float4 a4 = *(const float4*)(x + (long)qrow(g) * DD + lane * 4);
    const float qg = qInv[g];
    const int cb = g * CAND + w * 24;
    #pragma unroll 1
    for (int r = 0; r < 3; ++r) {
        const int c0 = cb + r * 8;
        int jj[8];
        #pragma unroll
        for (int u = 0; u < 8; u++) {
            int j = topi4[c0 + u];
            jj[u] = __builtin_amdgcn_readfirstlane(((unsigned)j < NQ) ? j : 0);
        }
        float4 b[8];
        #pragma unroll
        for (int u = 0; u < 8; u++)
            b[u] = *(const float4*)(x + (long)qrow(jj[u]) * DD + lane * 4);
        float p[8];
        #pragma unroll
        for (int u = 0; u < 8; u++)
            p[u] = a4.x * b[u].x + a4.y * b[u].y + a4.z * b[u].z + a4.w * b[u].w;
        #pragma unroll
        for (int off = 32; off > 0; off >>= 1) {
            #pragma unroll
            for (int u = 0; u < 8; u++) p[u] += __shfl_xor(p[u], off);
        }
        if (lane == 0) {
            const int cl = w * 24 + r * 8;
            #pragma unroll
            for (int u = 0; u < 8; u++) { sc[cl + u] = p[u] * qInv[jj[u]] * qg; si[cl + u] = jj[u]; }
        }
    }
    __syncthreads();
    if (t < 64) {
        float v0 = sc[lane];
        int   i0 = si[lane];
        float v1 = -INFINITY; int i1 = 0x7fffffff;
        if (lane < CAND - 64) { v1 = sc[64 + lane]; i1 = si[64 + lane]; }
        #pragma unroll 1
        for (int s = 0; s < KNB; ++s) {
            bool sel1 = (v1 > v0) || (v1 == v0 && i1 < i0);
            float bv = sel1 ? v1 : v0;
            int   bi = sel1 ? i1 : i0;
            #pragma unroll
            for (int off = 32; off > 0; off >>= 1) {
                float ov = __shfl_xor(bv, off);
                int   oi = __shfl_xor(bi, off);
                bool take = (ov > bv) || (ov == bv && oi < bi);
                bv = take ? ov : bv;
                bi = take ? oi : bi;
            }
            if (lane == 0) { topv[g * KNB + s] = bv; topi[g * KNB + s] = bi; }
            if (i0 == bi) v0 = -INFINITY;
            if (i1 == bi) v1 = -INFINITY;
        }
    }
}

// ---------- K6: mutual-kNN softmax, adapted query, final cos sims ----------
__global__ __launch_bounds__(256) void final_kernel(const float* __restrict__ x,
                                                    const float* __restrict__ apn,
                                                    const float* __restrict__ topv,
                                                    const int* __restrict__ topi,
                                                    const float* __restrict__ tao_raw,
                                                    float* out) {
    __shared__ float tv[KNB]; __shared__ int ti[KNB]; __shared__ float w[KNB];
    __shared__ __align__(16) float aq2[272];
    __shared__ float red4[4];
    __shared__ float part[256];
    int i = blockIdx.x, t = threadIdx.x;
    const int lane = t & 63, wv = t >> 6;
    if (t < KNB) {
        tv[t] = topv[i * KNB + t];
        int j = topi[i * KNB + t];
        ti[t] = ((unsigned)j < NQ) ? j : 0;
    }
    __syncthreads();
    if (t < KNB) {
        int j = ti[t];
        bool mut = false;
        for (int s = 0; s < KNB; s++) mut = mut || (topi[j * KNB + s] == i);
        w[t] = mut ? tv[t] : -INFINITY;
    }
    __syncthreads();
    if (t < 16) {                               // wave-parallel softmax (10 live)
        float val = (t < KNB) ? w[t] : -INFINITY;
        float m = val;
        #pragma unroll
        for (int off = 8; off > 0; off >>= 1) m = fmaxf(m, __shfl_xor(m, off));
        float e = (t < KNB) ? expf(val - m) : 0.f;
        float Z = e;
        #pragma unroll
        for (int off = 8; off > 0; off >>= 1) Z += __shfl_xor(Z, off);
        if (t < KNB) w[t] = e / Z;
    }
    __syncthreads();
    float a = 0.f;
    for (int s = 0; s < KNB; s++) {
        float ws = w[s];
        if (ws != 0.f) a += ws * x[(long)qrow(ti[s]) * DD + t];
    }
    aq2[t + (t >> 6) * 4] = a;
    float v2 = a * a;
    #pragma unroll
    for (int off = 32; off > 0; off >>= 1) v2 += __shfl_xor(v2, off);
    if (lane == 0) red4[wv] = v2;
    __syncthreads();                            // publishes aq2 + red4
    float n2 = red4[0] + red4[1] + red4[2] + red4[3];
    float inv = 1.f / sqrtf(n2);
    int c = t >> 2, tl = t & 3;
    float sdot = 0.f;
    const float* aqb = aq2 + tl * 68;
    const float4* ap4 = (const float4*)(apn + c * DD + tl * 64);
    #pragma unroll
    for (int u4 = 0; u4 < 16; u4++) {
        float4 av = *(const float4*)(aqb + u4 * 4);
        float4 pv = ap4[u4];
        sdot += av.x * pv.x; sdot += av.y * pv.y; sdot += av.z * pv.z; sdot += av.w * pv.w;
    }
    part[t] = sdot; __syncthreads();
    if (tl == 0) {
        float sv = part[t] + part[t + 1] + part[t + 2] + part[t + 3];
        out[i * NCLS + c] = tao_raw[0] * sv * inv;
    }
}

extern "C" void kernel_launch(void* const* d_in, const int* in_sizes, int n_in,
                              void* d_out, int out_size, void* d_ws, size_t ws_size,
                              hipStream_t stream) {
    (void)in_sizes; (void)n_in; (void)out_size;
    const float* x   = (const float*)d_in[0];
    const float* tao = (const float*)d_in[1];
    float* out = (float*)d_out;

    char* ws = (char*)d_ws;
    size_t off = 0;
    auto carve = [&](size_t bytes) {
        void* p = ws + off;
        off = (off + bytes + 255) & ~(size_t)255;
        return p;
    };
    float*          proto   = (float*)carve(NCLS * DD * 4);
    float*          pn      = (float*)carve(NCLS * DD * 4);
    float*          selfs   = (float*)carve(NCLS * 4);
    float*          qInv    = (float*)carve(NQ * 4);
    float*          pre_max = (float*)carve(NQ * 4);
    int*            pre_lab = (int*)carve(NQ * 4);
    float*          apn     = (float*)carve(NCLS * DD * 4);
    unsigned short* xh      = (unsigned short*)carve((size_t)NQ * DD * 2);
    int*            topi4   = (int*)carve((size_t)NQ * CAND * 4);
    float*          topv    = (float*)carve((size_t)NQ * KNB * 4);
    int*            topi    = (int*)carve((size_t)NQ * KNB * 4);
    if (off > ws_size) return;

    proto_kernel<<<NCLS, 256, 0, stream>>>(x, proto, pn, selfs);
    presim_kernel<<<NQ, 256, 0, stream>>>(x, pn, xh, qInv, pre_max, pre_lab);
    adapt_proto_kernel<<<NCLS, 256, 0, stream>>>(x, proto, selfs, pre_max, pre_lab, apn);
    simtopk_kernel<<<NQ / 64 * NCH, 256, 0, stream>>>(xh, topi4);
    rescore_kernel<<<NQ, 256, 0, stream>>>(x, qInv, topi4, topv, topi);
    final_kernel<<<NQ, 256, 0, stream>>>(x, apn, topv, topi, tao, out);
}

// Round 11
// 392.388 us; speedup vs baseline: 1.0538x; 1.0014x over previous
//
#include <hip/hip_runtime.h>
#include <math.h>

#define NCLS 64
#define KS 5
#define DD 256
#define NQ 8192   // NCLS*128
#define KNB 10
#define QK 12     // per-chunk candidate list depth (need >=10 for exact containment)
#define NCH 8     // column chunks per row (1024 cols each)
#define CAND 96   // NCH * QK

typedef __attribute__((ext_vector_type(8))) short short8;   // 8 bf16 bit-patterns (4 VGPRs)
typedef __attribute__((ext_vector_type(4))) float f32x4;    // MFMA C/D frag

// row index in x (fp32 row units) of query g
__device__ __forceinline__ int qrow(int g) { return (g >> 7) * 133 + KS + (g & 127); }

__device__ __forceinline__ unsigned short bf16_rne(float f) {
    unsigned int u = __float_as_uint(f);
    u += 0x7fffu + ((u >> 16) & 1u);
    return (unsigned short)(u >> 16);
}

__device__ __forceinline__ float blk_reduce_sum(float v, float* red) {
    int t = threadIdx.x;
    red[t] = v; __syncthreads();
    for (int off = 128; off > 0; off >>= 1) {
        if (t < off) red[t] += red[t + off];
        __syncthreads();
    }
    float r = red[0];
    __syncthreads();
    return r;
}

__device__ __forceinline__ float blk_reduce_max(float v, float* red) {
    int t = threadIdx.x;
    red[t] = v; __syncthreads();
    for (int off = 128; off > 0; off >>= 1) {
        if (t < off) red[t] = fmaxf(red[t], red[t + off]);
        __syncthreads();
    }
    float r = red[0];
    __syncthreads();
    return r;
}

// ---------- K1: proto, pn, self_sim ----------
__global__ __launch_bounds__(256) void proto_kernel(const float* __restrict__ x,
                                                    float* proto, float* pn, float* selfs) {
    __shared__ float red[256];
    int c = blockIdx.x, t = threadIdx.x;
    float s = 0.f;
    for (int j = 0; j < KS; j++) s += x[(long)(c * 133 + j) * DD + t];
    float p = s / 5.0f;
    proto[c * DD + t] = p;
    float n2 = blk_reduce_sum(p * p, red);
    float pv = p / sqrtf(n2);
    pn[c * DD + t] = pv;
    float ss = blk_reduce_sum(pv * pv, red);
    if (t == 0) selfs[c] = ss;
}

// ---------- K2: FUSED split + pre_sim argmax — low-barrier version ----------
__global__ __launch_bounds__(256) void presim_kernel(const float* __restrict__ x,
                                                     const float* __restrict__ pn,
                                                     unsigned short* __restrict__ xh,
                                                     float* __restrict__ qInv,
                                                     float* pre_max, int* pre_label) {
    __shared__ __align__(16) float qs2[272];
    __shared__ float red4[4];
    __shared__ float part[256];
    __shared__ float sims[64];
    int g = blockIdx.x, t = threadIdx.x;
    const int lane = t & 63, wv = t >> 6;
    float v = x[(long)qrow(g) * DD + t];
    qs2[t + (t >> 6) * 4] = v;
    float v2 = v * v;
    #pragma unroll
    for (int off = 32; off > 0; off >>= 1) v2 += __shfl_xor(v2, off);
    if (lane == 0) red4[wv] = v2;
    __syncthreads();                               // publishes qs2 + red4
    float n2 = red4[0] + red4[1] + red4[2] + red4[3];
    float inv = 1.f / sqrtf(n2);
    xh[g * DD + t] = bf16_rne(v * inv);
    if (t == 0) qInv[g] = inv;
    int c = t >> 2, tl = t & 3;
    float s = 0.f;
    const float* qb = qs2 + tl * 68;
    const float4* pp = (const float4*)(pn + c * DD + tl * 64);
    #pragma unroll
    for (int u4 = 0; u4 < 16; u4++) {
        float4 a = *(const float4*)(qb + u4 * 4);
        float4 b = pp[u4];
        s += a.x * b.x; s += a.y * b.y; s += a.z * b.z; s += a.w * b.w;
    }
    part[t] = s; __syncthreads();
    if (tl == 0) sims[c] = part[t] + part[t + 1] + part[t + 2] + part[t + 3];
    __syncthreads();
    if (t < 64) {
        float bv = sims[t]; int bi = t;
        #pragma unroll
        for (int off = 32; off > 0; off >>= 1) {
            float ov = __shfl_xor(bv, off);
            int   oi = __shfl_xor(bi, off);
            bool take = (ov > bv) || (ov == bv && oi < bi);
            bv = take ? ov : bv;
            bi = take ? oi : bi;
        }
        if (t == 0) { pre_max[g] = bv * inv; pre_label[g] = bi; }
    }
}

// ---------- K3: adapted prototypes — LDS-compacted member list ----------
__global__ __launch_bounds__(256) void adapt_proto_kernel(const float* __restrict__ x,
                                                          const float* __restrict__ proto,
                                                          const float* __restrict__ selfs,
                                                          const float* __restrict__ pre_max,
                                                          const int* __restrict__ pre_label,
                                                          float* apn) {
    __shared__ int lst[NQ];
    __shared__ float red[256];
    __shared__ int cnt_s;
    int c = blockIdx.x, t = threadIdx.x;
    if (t == 0) cnt_s = 0;
    __syncthreads();
    float lm = -INFINITY;
    for (int g = t; g < NQ; g += 256) {
        if (pre_label[g] == c) {
            int p = atomicAdd(&cnt_s, 1);
            lst[p] = g;
            lm = fmaxf(lm, pre_max[g]);
        }
    }
    float m = fmaxf(blk_reduce_max(lm, red), selfs[c]);   // barrier publishes lst/cnt_s
    int cnt = cnt_s;
    float ls = 0.f;
    for (int e = t; e < cnt; e += 256) ls += expf(pre_max[lst[e]] - m);
    float es = expf(selfs[c] - m);
    float Z = blk_reduce_sum(ls, red) + es;
    float a0 = es * proto[c * DD + t], a1 = 0.f, a2 = 0.f, a3 = 0.f;
    int e = 0;
    for (; e + 3 < cnt; e += 4) {
        int g0 = lst[e], g1 = lst[e + 1], g2 = lst[e + 2], g3 = lst[e + 3];
        float w0 = expf(pre_max[g0] - m), w1 = expf(pre_max[g1] - m);
        float w2 = expf(pre_max[g2] - m), w3 = expf(pre_max[g3] - m);
        a0 += w0 * x[(long)qrow(g0) * DD + t];
        a1 += w1 * x[(long)qrow(g1) * DD + t];
        a2 += w2 * x[(long)qrow(g2) * DD + t];
        a3 += w3 * x[(long)qrow(g3) * DD + t];
    }
    for (; e < cnt; e++) {
        int g0 = lst[e];
        a0 += expf(pre_max[g0] - m) * x[(long)qrow(g0) * DD + t];
    }
    float ap = ((a0 + a1) + (a2 + a3)) / Z;
    float n2 = blk_reduce_sum(ap * ap, red);
    apn[c * DD + t] = ap / sqrtf(n2);
}

// ---------- K4: bf16 MFMA coarse cosines — ILP/barrier surgery ----------
// R10: occupancy 31.7% of 50% cap = stall-bound. Three serial structures cut:
// (1) 2-tile buffers (2x16KB): 64 -> 32 barriers.
// (2) dual MFMA accumulators (even/odd kc): acc chain 8 -> 4 deep;
//     accE init 2.0, accO init 0.0 -> v = accE+accO in [1,3], monotone pack.
// (3) dual key lists per lane (r<2 -> keysA, r>=2 -> keysB): two independent
//     insert chains (ILP 2). Union unchanged, keys distinct (cid low bits),
//     8-way dump-merge yields the identical top-12 sequence.
#define INSERT_KEY(KEYS, KEY)                                                      \
    {                                                                              \
        unsigned int ck = (KEY);                                                   \
        _Pragma("unroll")                                                          \
        for (int p = 0; p < QK; ++p) {                                             \
            unsigned int tmp = KEYS[p];                                            \
            KEYS[p] = tmp > ck ? tmp : ck;   /* v_max_u32 */                       \
            ck = tmp > ck ? ck : tmp;        /* v_min_u32 */                       \
        }                                                                          \
    }

#define COMPUTE_TILE_L(LBUF, TILE)                                                 \
    {                                                                              \
        f32x4 accE = {2.f, 2.f, 2.f, 2.f};                                         \
        f32x4 accO = {0.f, 0.f, 0.f, 0.f};                                         \
        _Pragma("unroll")                                                          \
        for (int kc = 0; kc < 8; kc += 2) {                                        \
            short8 cfe = *(const short8*)((LBUF) + ((nn << 8) + ((((kc + 0) * 4 + qd) ^ xm) << 3))); \
            short8 cfo = *(const short8*)((LBUF) + ((nn << 8) + ((((kc + 1) * 4 + qd) ^ xm) << 3))); \
            accE = __builtin_amdgcn_mfma_f32_16x16x32_bf16(cfe, qh[kc + 0], accE, 0, 0, 0); \
            accO = __builtin_amdgcn_mfma_f32_16x16x32_bf16(cfo, qh[kc + 1], accO, 0, 0, 0); \
        }                                                                          \
        _Pragma("unroll")                                                          \
        for (int r = 0; r < 2; ++r) {                                              \
            float v = accE[r] + accO[r];                                           \
            unsigned int cid = (unsigned int)((TILE) * 16 + 4 * qd + r);           \
            unsigned int k0 = (__float_as_uint(v) & 0xFFFFFC00u) | cid;            \
            INSERT_KEY(keysA, k0)                                                  \
        }                                                                          \
        _Pragma("unroll")                                                          \
        for (int r = 2; r < 4; ++r) {                                              \
            float v = accE[r] + accO[r];                                           \
            unsigned int cid = (unsigned int)((TILE) * 16 + 4 * qd + r);           \
            unsigned int k0 = (__float_as_uint(v) & 0xFFFFFC00u) | cid;            \
            INSERT_KEY(keysB, k0)                                                  \
        }                                                                          \
    }

#define GLOAD(RA, RB, TL)                                                          \
    {                                                                              \
        const unsigned short* tb = xh + ((size_t)(col0 + (TL) * 16) << 8);         \
        RA = *(const uint4*)(tb + (G0 << 3));                                      \
        RB = *(const uint4*)(tb + (G1 << 3));                                      \
    }

#define DSWRITE(P, RA, RB)                                                         \
    {                                                                              \
        *(uint4*)((P) + (u0 << 3)) = RA;                                           \
        *(uint4*)((P) + (u1 << 3)) = RB;                                           \
    }

__global__ __launch_bounds__(256, 4) void simtopk_kernel(const unsigned short* __restrict__ xh,
                                                         int* __restrict__ topi4) {
    __shared__ uint4 smem4[2048];   // 32 KB: 2 buffers x 2 tiles; dump alias 26.6KB
    unsigned short* Tb = (unsigned short*)smem4;

    const int t = threadIdx.x;
    const int b = blockIdx.x;
    const int rb = b >> 3;          // 128 row-blocks of 64 rows
    const int ch = b & 7;           // column chunk (== XCD id under round-robin: L2-local)
    const int row0 = rb * 64;
    const int col0 = ch * 1024;

    const int wv = t >> 6;
    const int lane = t & 63;
    const int qd = lane >> 4;
    const int nn = lane & 15;
    const int xm = nn & 7;

    // staging geometry: tile = 512 x 16B units; thread handles G0=t, G1=256+t
    const int G0 = t, G1 = 256 + t;
    const int r0r = G0 >> 5, c0u = G0 & 31;
    const int u0 = r0r * 32 + (c0u ^ (r0r & 7));
    const int r1r = G1 >> 5, c1u = G1 & 31;
    const int u1 = r1r * 32 + (c1u ^ (r1r & 7));

    // Query fragments (MFMA B operand): lane holds Q[n=nn][k=kc*32+qd*8 ..+7]
    const int arow = (row0 + wv * 16 + nn) * DD;
    short8 qh[8];
    #pragma unroll
    for (int kc = 0; kc < 8; kc++)
        qh[kc] = *(const short8*)(xh + arow + kc * 32 + qd * 8);

    unsigned int keysA[QK], keysB[QK];
    #pragma unroll
    for (int s = 0; s < QK; s++) { keysA[s] = 0u; keysB[s] = 0u; }

    uint4 RA, RB, RC, RD;
    GLOAD(RA, RB, 0)
    GLOAD(RC, RD, 1)
    DSWRITE(Tb, RA, RB)
    DSWRITE(Tb + 4096, RC, RD)
    __syncthreads();                         // tiles 0,1 ready in buffer 0

    #pragma unroll 1
    for (int p = 0; p < 32; ++p) {
        const int cur = (p & 1) << 13;       // 0 / 8192 shorts (16KB buffers)
        if (p < 31) { GLOAD(RA, RB, 2 * p + 2) GLOAD(RC, RD, 2 * p + 3) }
        COMPUTE_TILE_L(Tb + cur, 2 * p)
        COMPUTE_TILE_L(Tb + cur + 4096, 2 * p + 1)
        if (p < 31) {
            DSWRITE(Tb + (cur ^ 8192), RA, RB)
            DSWRITE(Tb + (cur ^ 8192) + 4096, RC, RD)
        }
        __syncthreads();                     // publishes pair p+1; orders reads of pair p
    }

    // dump both lists (wave-private region, in-order DS: no barrier) + 8-way merge.
    unsigned int* dw = (unsigned int*)smem4 + wv * 1664;
    unsigned int* dwB = dw + 832;
    #pragma unroll
    for (int s = 0; s < QK; s++) dw[lane * 13 + s] = keysA[s];
    #pragma unroll
    for (int s = 0; s < QK; s++) dwB[lane * 13 + s] = keysB[s];
    if (lane < 16) {
        const int g = row0 + wv * 16 + lane;
        const int b0 = (lane +  0) * 13;
        const int b1 = (lane + 16) * 13;
        const int b2 = (lane + 32) * 13;
        const int b3 = (lane + 48) * 13;
        int p0 = 0, p1 = 0, p2 = 0, p3 = 0, p4 = 0, p5 = 0, p6 = 0, p7 = 0;
        for (int s = 0; s < QK; s++) {
            unsigned int v0 = (p0 < QK) ? dw[b0 + p0]  : 0u;
            unsigned int v1 = (p1 < QK) ? dw[b1 + p1]  : 0u;
            unsigned int v2 = (p2 < QK) ? dw[b2 + p2]  : 0u;
            unsigned int v3 = (p3 < QK) ? dw[b3 + p3]  : 0u;
            unsigned int v4 = (p4 < QK) ? dwB[b0 + p4] : 0u;
            unsigned int v5 = (p5 < QK) ? dwB[b1 + p5] : 0u;
            unsigned int v6 = (p6 < QK) ? dwB[b2 + p6] : 0u;
            unsigned int v7 = (p7 < QK) ? dwB[b3 + p7] : 0u;
            unsigned int bv = v0; int bw = 0;
            if (v1 > bv) { bv = v1; bw = 1; }
            if (v2 > bv) { bv = v2; bw = 2; }
            if (v3 > bv) { bv = v3; bw = 3; }
            if (v4 > bv) { bv = v4; bw = 4; }
            if (v5 > bv) { bv = v5; bw = 5; }
            if (v6 > bv) { bv = v6; bw = 6; }
            if (v7 > bv) { bv = v7; bw = 7; }
            topi4[g * CAND + ch * QK + s] = col0 + (int)(bv & 1023u);
            if      (bw == 0) p0++; else if (bw == 1) p1++;
            else if (bw == 2) p2++; else if (bw == 3) p3++;
            else if (bw == 4) p4++; else if (bw == 5) p5++;
            else if (bw == 6) p6++; else p7++;
        }
    }
}

// ---------- K5: FUSED exact fp32 rescoring + wave-parallel top-10 ----------
__global__ __launch_bounds__(256, 4) void rescore_kernel(const float* __restrict__ x,
                                                         const float* __restrict__ qInv,
                                                         const int* __restrict__ topi4,
                                                         float* __restrict__ topv,
                                                         int* __restrict__ topi) {
    __shared__ float sc[CAND];
    __shared__ int   si[CAND];
    const int g = blockIdx.x;
    const int t = threadIdx.x;
    const int lane = t & 63;
    const int w = t >> 6;            // wave's candidate group [24w, 24w+24)
    const float4 a4 = *(const float4*)(x + (long)qrow(g) * DD + lane * 4);
    const float qg = qInv[g];
    const int cb = g * CAND + w * 24;
    #pragma unroll 1
    for (int r = 0; r < 3; ++r) {
        const int c0 = cb + r * 8;
        int jj[8];
        #pragma unroll
        for (int u = 0; u < 8; u++) {
            int j = topi4[c0 + u];
            jj[u] = __builtin_amdgcn_readfirstlane(((unsigned)j < NQ) ? j : 0);
        }
        float4 b[8];
        #pragma unroll
        for (int u = 0; u < 8; u++)
            b[u] = *(const float4*)(x + (long)qrow(jj[u]) * DD + lane * 4);
        float p[8];
        #pragma unroll
        for (int u = 0; u < 8; u++)
            p[u] = a4.x * b[u].x + a4.y * b[u].y + a4.z * b[u].z + a4.w * b[u].w;
        #pragma unroll
        for (int off = 32; off > 0; off >>= 1) {
            #pragma unroll
            for (int u = 0; u < 8; u++) p[u] += __shfl_xor(p[u], off);
        }
        if (lane == 0) {
            const int cl = w * 24 + r * 8;
            #pragma unroll
            for (int u = 0; u < 8; u++) { sc[cl + u] = p[u] * qInv[jj[u]] * qg; si[cl + u] = jj[u]; }
        }
    }
    __syncthreads();
    if (t < 64) {
        float v0 = sc[lane];
        int   i0 = si[lane];
        float v1 = -INFINITY; int i1 = 0x7fffffff;
        if (lane < CAND - 64) { v1 = sc[64 + lane]; i1 = si[64 + lane]; }
        #pragma unroll 1
        for (int s = 0; s < KNB; ++s) {
            bool sel1 = (v1 > v0) || (v1 == v0 && i1 < i0);
            float bv = sel1 ? v1 : v0;
            int   bi = sel1 ? i1 : i0;
            #pragma unroll
            for (int off = 32; off > 0; off >>= 1) {
                float ov = __shfl_xor(bv, off);
                int   oi = __shfl_xor(bi, off);
                bool take = (ov > bv) || (ov == bv && oi < bi);
                bv = take ? ov : bv;
                bi = take ? oi : bi;
            }
            if (lane == 0) { topv[g * KNB + s] = bv; topi[g * KNB + s] = bi; }
            if (i0 == bi) v0 = -INFINITY;
            if (i1 == bi) v1 = -INFINITY;
        }
    }
}

// ---------- K6: mutual-kNN softmax, adapted query, final cos sims ----------
__global__ __launch_bounds__(256) void final_kernel(const float* __restrict__ x,
                                                    const float* __restrict__ apn,
                                                    const float* __restrict__ topv,
                                                    const int* __restrict__ topi,
                                                    const float* __restrict__ tao_raw,
                                                    float* out) {
    __shared__ float tv[KNB]; __shared__ int ti[KNB]; __shared__ float w[KNB];
    __shared__ __align__(16) float aq2[272];
    __shared__ float red4[4];
    __shared__ float part[256];
    int i = blockIdx.x, t = threadIdx.x;
    const int lane = t & 63, wv = t >> 6;
    if (t < KNB) {
        tv[t] = topv[i * KNB + t];
        int j = topi[i * KNB + t];
        ti[t] = ((unsigned)j < NQ) ? j : 0;
    }
    __syncthreads();
    if (t < KNB) {
        int j = ti[t];
        bool mut = false;
        for (int s = 0; s < KNB; s++) mut = mut || (topi[j * KNB + s] == i);
        w[t] = mut ? tv[t] : -INFINITY;
    }
    __syncthreads();
    if (t < 16) {                               // wave-parallel softmax (10 live)
        float val = (t < KNB) ? w[t] : -INFINITY;
        float m = val;
        #pragma unroll
        for (int off = 8; off > 0; off >>= 1) m = fmaxf(m, __shfl_xor(m, off));
        float e = (t < KNB) ? expf(val - m) : 0.f;
        float Z = e;
        #pragma unroll
        for (int off = 8; off > 0; off >>= 1) Z += __shfl_xor(Z, off);
        if (t < KNB) w[t] = e / Z;
    }
    __syncthreads();
    float a = 0.f;
    for (int s = 0; s < KNB; s++) {
        float ws = w[s];
        if (ws != 0.f) a += ws * x[(long)qrow(ti[s]) * DD + t];
    }
    aq2[t + (t >> 6) * 4] = a;
    float v2 = a * a;
    #pragma unroll
    for (int off = 32; off > 0; off >>= 1) v2 += __shfl_xor(v2, off);
    if (lane == 0) red4[wv] = v2;
    __syncthreads();                            // publishes aq2 + red4
    float n2 = red4[0] + red4[1] + red4[2] + red4[3];
    float inv = 1.f / sqrtf(n2);
    int c = t >> 2, tl = t & 3;
    float sdot = 0.f;
    const float* aqb = aq2 + tl * 68;
    const float4* ap4 = (const float4*)(apn + c * DD + tl * 64);
    #pragma unroll
    for (int u4 = 0; u4 < 16; u4++) {
        float4 av = *(const float4*)(aqb + u4 * 4);
        float4 pv = ap4[u4];
        sdot += av.x * pv.x; sdot += av.y * pv.y; sdot += av.z * pv.z; sdot += av.w * pv.w;
    }
    part[t] = sdot; __syncthreads();
    if (tl == 0) {
        float sv = part[t] + part[t + 1] + part[t + 2] + part[t + 3];
        out[i * NCLS + c] = tao_raw[0] * sv * inv;
    }
}

extern "C" void kernel_launch(void* const* d_in, const int* in_sizes, int n_in,
                              void* d_out, int out_size, void* d_ws, size_t ws_size,
                              hipStream_t stream) {
    (void)in_sizes; (void)n_in; (void)out_size;
    const float* x   = (const float*)d_in[0];
    const float* tao = (const float*)d_in[1];
    float* out = (float*)d_out;

    char* ws = (char*)d_ws;
    size_t off = 0;
    auto carve = [&](size_t bytes) {
        void* p = ws + off;
        off = (off + bytes + 255) & ~(size_t)255;
        return p;
    };
    float*          proto   = (float*)carve(NCLS * DD * 4);
    float*          pn      = (float*)carve(NCLS * DD * 4);
    float*          selfs   = (float*)carve(NCLS * 4);
    float*          qInv    = (float*)carve(NQ * 4);
    float*          pre_max = (float*)carve(NQ * 4);
    int*            pre_lab = (int*)carve(NQ * 4);
    float*          apn     = (float*)carve(NCLS * DD * 4);
    unsigned short* xh      = (unsigned short*)carve((size_t)NQ * DD * 2);
    int*            topi4   = (int*)carve((size_t)NQ * CAND * 4);
    float*          topv    = (float*)carve((size_t)NQ * KNB * 4);
    int*            topi    = (int*)carve((size_t)NQ * KNB * 4);
    if (off > ws_size) return;

    proto_kernel<<<NCLS, 256, 0, stream>>>(x, proto, pn, selfs);
    presim_kernel<<<NQ, 256, 0, stream>>>(x, pn, xh, qInv, pre_max, pre_lab);
    adapt_proto_kernel<<<NCLS, 256, 0, stream>>>(x, proto, selfs, pre_max, pre_lab, apn);
    simtopk_kernel<<<NQ / 64 * NCH, 256, 0, stream>>>(xh, topi4);
    rescore_kernel<<<NQ, 256, 0, stream>>>(x, qInv, topi4, topv, topi);
    final_kernel<<<NQ, 256, 0, stream>>>(x, apn, topv, topi, tao, out);
}

// Round 12
// 376.391 us; speedup vs baseline: 1.0986x; 1.0425x over previous
//
#include <hip/hip_runtime.h>
#include <math.h>

#define NCLS 64
#define KS 5
#define DD 256
#define NQ 8192   // NCLS*128
#define KNB 10
#define QK 12     // per-chunk candidate list depth (need >=10 for exact containment)
#define NCH 8     // column chunks per row (1024 cols each)
#define CAND 96   // NCH * QK

typedef __attribute__((ext_vector_type(8))) short short8;   // 8 bf16 bit-patterns (4 VGPRs)
typedef __attribute__((ext_vector_type(4))) float f32x4;    // MFMA C/D frag

// row index in x (fp32 row units) of query g
__device__ __forceinline__ int qrow(int g) { return (g >> 7) * 133 + KS + (g & 127); }

__device__ __forceinline__ unsigned short bf16_rne(float f) {
    unsigned int u = __float_as_uint(f);
    u += 0x7fffu + ((u >> 16) & 1u);
    return (unsigned short)(u >> 16);
}

__device__ __forceinline__ float blk_reduce_sum(float v, float* red) {
    int t = threadIdx.x;
    red[t] = v; __syncthreads();
    for (int off = 128; off > 0; off >>= 1) {
        if (t < off) red[t] += red[t + off];
        __syncthreads();
    }
    float r = red[0];
    __syncthreads();
    return r;
}

__device__ __forceinline__ float blk_reduce_max(float v, float* red) {
    int t = threadIdx.x;
    red[t] = v; __syncthreads();
    for (int off = 128; off > 0; off >>= 1) {
        if (t < off) red[t] = fmaxf(red[t], red[t + off]);
        __syncthreads();
    }
    float r = red[0];
    __syncthreads();
    return r;
}

// ---------- K1: proto, pn, self_sim ----------
__global__ __launch_bounds__(256) void proto_kernel(const float* __restrict__ x,
                                                    float* proto, float* pn, float* selfs) {
    __shared__ float red[256];
    int c = blockIdx.x, t = threadIdx.x;
    float s = 0.f;
    for (int j = 0; j < KS; j++) s += x[(long)(c * 133 + j) * DD + t];
    float p = s / 5.0f;
    proto[c * DD + t] = p;
    float n2 = blk_reduce_sum(p * p, red);
    float pv = p / sqrtf(n2);
    pn[c * DD + t] = pv;
    float ss = blk_reduce_sum(pv * pv, red);
    if (t == 0) selfs[c] = ss;
}

// ---------- K2: FUSED split + pre_sim argmax — low-barrier version ----------
__global__ __launch_bounds__(256) void presim_kernel(const float* __restrict__ x,
                                                     const float* __restrict__ pn,
                                                     unsigned short* __restrict__ xh,
                                                     float* __restrict__ qInv,
                                                     float* pre_max, int* pre_label) {
    __shared__ __align__(16) float qs2[272];
    __shared__ float red4[4];
    __shared__ float part[256];
    __shared__ float sims[64];
    int g = blockIdx.x, t = threadIdx.x;
    const int lane = t & 63, wv = t >> 6;
    float v = x[(long)qrow(g) * DD + t];
    qs2[t + (t >> 6) * 4] = v;
    float v2 = v * v;
    #pragma unroll
    for (int off = 32; off > 0; off >>= 1) v2 += __shfl_xor(v2, off);
    if (lane == 0) red4[wv] = v2;
    __syncthreads();                               // publishes qs2 + red4
    float n2 = red4[0] + red4[1] + red4[2] + red4[3];
    float inv = 1.f / sqrtf(n2);
    xh[g * DD + t] = bf16_rne(v * inv);
    if (t == 0) qInv[g] = inv;
    int c = t >> 2, tl = t & 3;
    float s = 0.f;
    const float* qb = qs2 + tl * 68;
    const float4* pp = (const float4*)(pn + c * DD + tl * 64);
    #pragma unroll
    for (int u4 = 0; u4 < 16; u4++) {
        float4 a = *(const float4*)(qb + u4 * 4);
        float4 b = pp[u4];
        s += a.x * b.x; s += a.y * b.y; s += a.z * b.z; s += a.w * b.w;
    }
    part[t] = s; __syncthreads();
    if (tl == 0) sims[c] = part[t] + part[t + 1] + part[t + 2] + part[t + 3];
    __syncthreads();
    if (t < 64) {
        float bv = sims[t]; int bi = t;
        #pragma unroll
        for (int off = 32; off > 0; off >>= 1) {
            float ov = __shfl_xor(bv, off);
            int   oi = __shfl_xor(bi, off);
            bool take = (ov > bv) || (ov == bv && oi < bi);
            bv = take ? ov : bv;
            bi = take ? oi : bi;
        }
        if (t == 0) { pre_max[g] = bv * inv; pre_label[g] = bi; }
    }
}

// ---------- K3: adapted prototypes — LDS-compacted member list ----------
__global__ __launch_bounds__(256) void adapt_proto_kernel(const float* __restrict__ x,
                                                          const float* __restrict__ proto,
                                                          const float* __restrict__ selfs,
                                                          const float* __restrict__ pre_max,
                                                          const int* __restrict__ pre_label,
                                                          float* apn) {
    __shared__ int lst[NQ];
    __shared__ float red[256];
    __shared__ int cnt_s;
    int c = blockIdx.x, t = threadIdx.x;
    if (t == 0) cnt_s = 0;
    __syncthreads();
    float lm = -INFINITY;
    for (int g = t; g < NQ; g += 256) {
        if (pre_label[g] == c) {
            int p = atomicAdd(&cnt_s, 1);
            lst[p] = g;
            lm = fmaxf(lm, pre_max[g]);
        }
    }
    float m = fmaxf(blk_reduce_max(lm, red), selfs[c]);   // barrier publishes lst/cnt_s
    int cnt = cnt_s;
    float ls = 0.f;
    for (int e = t; e < cnt; e += 256) ls += expf(pre_max[lst[e]] - m);
    float es = expf(selfs[c] - m);
    float Z = blk_reduce_sum(ls, red) + es;
    float a0 = es * proto[c * DD + t], a1 = 0.f, a2 = 0.f, a3 = 0.f;
    int e = 0;
    for (; e + 3 < cnt; e += 4) {
        int g0 = lst[e], g1 = lst[e + 1], g2 = lst[e + 2], g3 = lst[e + 3];
        float w0 = expf(pre_max[g0] - m), w1 = expf(pre_max[g1] - m);
        float w2 = expf(pre_max[g2] - m), w3 = expf(pre_max[g3] - m);
        a0 += w0 * x[(long)qrow(g0) * DD + t];
        a1 += w1 * x[(long)qrow(g1) * DD + t];
        a2 += w2 * x[(long)qrow(g2) * DD + t];
        a3 += w3 * x[(long)qrow(g3) * DD + t];
    }
    for (; e < cnt; e++) {
        int g0 = lst[e];
        a0 += expf(pre_max[g0] - m) * x[(long)qrow(g0) * DD + t];
    }
    float ap = ((a0 + a1) + (a2 + a3)) / Z;
    float n2 = blk_reduce_sum(ap * ap, red);
    apn[c * DD + t] = ap / sqrtf(n2);
}

// ---------- K4: bf16 MFMA coarse cosines — BATCH-BITONIC top-12 scan ----------
// R11: VALU issue-bound (busy 60us/94us). Sequential bubble insert = 96 ops
// per tile (4 values x 12 CAS). Replace with batch insert: sort the 4 new
// keys ASC (5 CAS), concat with sorted-desc keys[12] -> 16-elem bitonic
// valley -> split16 (4 CAS; the 4 L[0..3]vsL[8..11] comparators are provable
// no-ops), bitonic-sort top-8 (12 CAS), split bottom-8 for its top-4 (4
// max-only), sort those (4 CAS) = 54 ops. EXACT same top-12 set+order
// (distinct keys via cid bits). Single list again (dual lists were zero-gain:
// each still needed depth 12). Dual accumulators + 2-tile pairs kept.
#define CASD(A, B) { unsigned int _x = (A), _y = (B); (A) = _x > _y ? _x : _y; (B) = _x > _y ? _y : _x; }
#define CASA(A, B) { unsigned int _x = (A), _y = (B); (A) = _x < _y ? _x : _y; (B) = _x < _y ? _y : _x; }

#define COMPUTE_TILE_L(LBUF, TILE)                                                 \
    {                                                                              \
        f32x4 accE = {2.f, 2.f, 2.f, 2.f};                                         \
        f32x4 accO = {0.f, 0.f, 0.f, 0.f};                                         \
        _Pragma("unroll")                                                          \
        for (int kc = 0; kc < 8; kc += 2) {                                        \
            short8 cfe = *(const short8*)((LBUF) + ((nn << 8) + ((((kc + 0) * 4 + qd) ^ xm) << 3))); \
            short8 cfo = *(const short8*)((LBUF) + ((nn << 8) + ((((kc + 1) * 4 + qd) ^ xm) << 3))); \
            accE = __builtin_amdgcn_mfma_f32_16x16x32_bf16(cfe, qh[kc + 0], accE, 0, 0, 0); \
            accO = __builtin_amdgcn_mfma_f32_16x16x32_bf16(cfo, qh[kc + 1], accO, 0, 0, 0); \
        }                                                                          \
        const unsigned int cb_ = (unsigned int)((TILE) * 16 + 4 * qd);             \
        unsigned int v0 = (__float_as_uint(accE[0] + accO[0]) & 0xFFFFFC00u) | (cb_ + 0); \
        unsigned int v1 = (__float_as_uint(accE[1] + accO[1]) & 0xFFFFFC00u) | (cb_ + 1); \
        unsigned int v2 = (__float_as_uint(accE[2] + accO[2]) & 0xFFFFFC00u) | (cb_ + 2); \
        unsigned int v3 = (__float_as_uint(accE[3] + accO[3]) & 0xFFFFFC00u) | (cb_ + 3); \
        /* sort batch ascending: v0<=v1<=v2<=v3 */                                 \
        CASA(v0, v1) CASA(v2, v3) CASA(v0, v2) CASA(v1, v3) CASA(v1, v2)           \
        /* split16 (valley keys[0..11]++v[0..3]); (i,i+8) for i<4 are no-ops */    \
        unsigned int t4 = keys[4], t5 = keys[5], t6 = keys[6], t7 = keys[7];       \
        unsigned int b4 = t4 < v0 ? t4 : v0; t4 = t4 > v0 ? t4 : v0;               \
        unsigned int b5 = t5 < v1 ? t5 : v1; t5 = t5 > v1 ? t5 : v1;               \
        unsigned int b6 = t6 < v2 ? t6 : v2; t6 = t6 > v2 ? t6 : v2;               \
        unsigned int b7 = t7 < v3 ? t7 : v3; t7 = t7 > v3 ? t7 : v3;               \
        /* sort top-8 [keys0..3, t4..7] desc (bitonic) */                          \
        CASD(keys[0], t4) CASD(keys[1], t5) CASD(keys[2], t6) CASD(keys[3], t7)    \
        CASD(keys[0], keys[2]) CASD(keys[1], keys[3]) CASD(t4, t6) CASD(t5, t7)    \
        CASD(keys[0], keys[1]) CASD(keys[2], keys[3]) CASD(t4, t5) CASD(t6, t7)    \
        keys[4] = t4; keys[5] = t5; keys[6] = t6; keys[7] = t7;                    \
        /* bottom-8 [keys8..11, b4..7] bitonic: top-4 via split (max only) */      \
        unsigned int B0 = keys[8]  > b4 ? keys[8]  : b4;                           \
        unsigned int B1 = keys[9]  > b5 ? keys[9]  : b5;                           \
        unsigned int B2 = keys[10] > b6 ? keys[10] : b6;                           \
        unsigned int B3 = keys[11] > b7 ? keys[11] : b7;                           \
        CASD(B0, B2) CASD(B1, B3) CASD(B0, B1) CASD(B2, B3)                        \
        keys[8] = B0; keys[9] = B1; keys[10] = B2; keys[11] = B3;                  \
    }

#define GLOAD(RA, RB, TL)                                                          \
    {                                                                              \
        const unsigned short* tb = xh + ((size_t)(col0 + (TL) * 16) << 8);         \
        RA = *(const uint4*)(tb + (G0 << 3));                                      \
        RB = *(const uint4*)(tb + (G1 << 3));                                      \
    }

#define DSWRITE(P, RA, RB)                                                         \
    {                                                                              \
        *(uint4*)((P) + (u0 << 3)) = RA;                                           \
        *(uint4*)((P) + (u1 << 3)) = RB;                                           \
    }

__global__ __launch_bounds__(256, 4) void simtopk_kernel(const unsigned short* __restrict__ xh,
                                                         int* __restrict__ topi4) {
    __shared__ uint4 smem4[2048];   // 32 KB: 2 buffers x 2 tiles; dump alias 13.3KB
    unsigned short* Tb = (unsigned short*)smem4;

    const int t = threadIdx.x;
    const int b = blockIdx.x;
    const int rb = b >> 3;          // 128 row-blocks of 64 rows
    const int ch = b & 7;           // column chunk (== XCD id under round-robin: L2-local)
    const int row0 = rb * 64;
    const int col0 = ch * 1024;

    const int wv = t >> 6;
    const int lane = t & 63;
    const int qd = lane >> 4;
    const int nn = lane & 15;
    const int xm = nn & 7;

    // staging geometry: tile = 512 x 16B units; thread handles G0=t, G1=256+t
    const int G0 = t, G1 = 256 + t;
    const int r0r = G0 >> 5, c0u = G0 & 31;
    const int u0 = r0r * 32 + (c0u ^ (r0r & 7));
    const int r1r = G1 >> 5, c1u = G1 & 31;
    const int u1 = r1r * 32 + (c1u ^ (r1r & 7));

    // Query fragments (MFMA B operand): lane holds Q[n=nn][k=kc*32+qd*8 ..+7]
    const int arow = (row0 + wv * 16 + nn) * DD;
    short8 qh[8];
    #pragma unroll
    for (int kc = 0; kc < 8; kc++)
        qh[kc] = *(const short8*)(xh + arow + kc * 32 + qd * 8);

    unsigned int keys[QK];
    #pragma unroll
    for (int s = 0; s < QK; s++) keys[s] = 0u;

    uint4 RA, RB, RC, RD;
    GLOAD(RA, RB, 0)
    GLOAD(RC, RD, 1)
    DSWRITE(Tb, RA, RB)
    DSWRITE(Tb + 4096, RC, RD)
    __syncthreads();                         // tiles 0,1 ready in buffer 0

    #pragma unroll 1
    for (int p = 0; p < 32; ++p) {
        const int cur = (p & 1) << 13;       // 0 / 8192 shorts (16KB buffers)
        if (p < 31) { GLOAD(RA, RB, 2 * p + 2) GLOAD(RC, RD, 2 * p + 3) }
        COMPUTE_TILE_L(Tb + cur, 2 * p)
        COMPUTE_TILE_L(Tb + cur + 4096, 2 * p + 1)
        if (p < 31) {
            DSWRITE(Tb + (cur ^ 8192), RA, RB)
            DSWRITE(Tb + (cur ^ 8192) + 4096, RC, RD)
        }
        __syncthreads();                     // publishes pair p+1; orders reads of pair p
    }

    // dump (wave-private region, in-order DS: no barrier) + 4-list merge.
    unsigned int* dw = (unsigned int*)smem4 + wv * 832;
    #pragma unroll
    for (int s = 0; s < QK; s++) dw[lane * 13 + s] = keys[s];
    if (lane < 16) {
        const int g = row0 + wv * 16 + lane;
        const int b0 = (lane +  0) * 13;
        const int b1 = (lane + 16) * 13;
        const int b2 = (lane + 32) * 13;
        const int b3 = (lane + 48) * 13;
        int p0 = 0, p1 = 0, p2 = 0, p3 = 0;
        for (int s = 0; s < QK; s++) {
            unsigned int v0 = (p0 < QK) ? dw[b0 + p0] : 0u;
            unsigned int v1 = (p1 < QK) ? dw[b1 + p1] : 0u;
            unsigned int v2 = (p2 < QK) ? dw[b2 + p2] : 0u;
            unsigned int v3 = (p3 < QK) ? dw[b3 + p3] : 0u;
            unsigned int bv = v0; int bw = 0;
            if (v1 > bv) { bv = v1; bw = 1; }
            if (v2 > bv) { bv = v2; bw = 2; }
            if (v3 > bv) { bv = v3; bw = 3; }
            topi4[g * CAND + ch * QK + s] = col0 + (int)(bv & 1023u);
            if (bw == 0) p0++; else if (bw == 1) p1++; else if (bw == 2) p2++; else p3++;
        }
    }
}

// ---------- K5: FUSED exact fp32 rescoring + wave-parallel top-10 ----------
__global__ __launch_bounds__(256, 4) void rescore_kernel(const float* __restrict__ x,
                                                         const float* __restrict__ qInv,
                                                         const int* __restrict__ topi4,
                                                         float* __restrict__ topv,
                                                         int* __restrict__ topi) {
    __shared__ float sc[CAND];
    __shared__ int   si[CAND];
    const int g = blockIdx.x;
    const int t = threadIdx.x;
    const int lane = t & 63;
    const int w = t >> 6;            // wave's candidate group [24w, 24w+24)
    const float4 a4 = *(const float4*)(x + (long)qrow(g) * DD + lane * 4);
    const float qg = qInv[g];
    const int cb = g * CAND + w * 24;
    #pragma unroll 1
    for (int r = 0; r < 3; ++r) {
        const int c0 = cb + r * 8;
        int jj[8];
        #pragma unroll
        for (int u = 0; u < 8; u++) {
            int j = topi4[c0 + u];
            jj[u] = __builtin_amdgcn_readfirstlane(((unsigned)j < NQ) ? j : 0);
        }
        float4 b[8];
        #pragma unroll
        for (int u = 0; u < 8; u++)
            b[u] = *(const float4*)(x + (long)qrow(jj[u]) * DD + lane * 4);
        float p[8];
        #pragma unroll
        for (int u = 0; u < 8; u++)
            p[u] = a4.x * b[u].x + a4.y * b[u].y + a4.z * b[u].z + a4.w * b[u].w;
        #pragma unroll
        for (int off = 32; off > 0; off >>= 1) {
            #pragma unroll
            for (int u = 0; u < 8; u++) p[u] += __shfl_xor(p[u], off);
        }
        if (lane == 0) {
            const int cl = w * 24 + r * 8;
            #pragma unroll
            for (int u = 0; u < 8; u++) { sc[cl + u] = p[u] * qInv[jj[u]] * qg; si[cl + u] = jj[u]; }
        }
    }
    __syncthreads();
    if (t < 64) {
        float v0 = sc[lane];
        int   i0 = si[lane];
        float v1 = -INFINITY; int i1 = 0x7fffffff;
        if (lane < CAND - 64) { v1 = sc[64 + lane]; i1 = si[64 + lane]; }
        #pragma unroll 1
        for (int s = 0; s < KNB; ++s) {
            bool sel1 = (v1 > v0) || (v1 == v0 && i1 < i0);
            float bv = sel1 ? v1 : v0;
            int   bi = sel1 ? i1 : i0;
            #pragma unroll
            for (int off = 32; off > 0; off >>= 1) {
                float ov = __shfl_xor(bv, off);
                int   oi = __shfl_xor(bi, off);
                bool take = (ov > bv) || (ov == bv && oi < bi);
                bv = take ? ov : bv;
                bi = take ? oi : bi;
            }
            if (lane == 0) { topv[g * KNB + s] = bv; topi[g * KNB + s] = bi; }
            if (i0 == bi) v0 = -INFINITY;
            if (i1 == bi) v1 = -INFINITY;
        }
    }
}

// ---------- K6: mutual-kNN softmax, adapted query, final cos sims ----------
__global__ __launch_bounds__(256) void final_kernel(const float* __restrict__ x,
                                                    const float* __restrict__ apn,
                                                    const float* __restrict__ topv,
                                                    const int* __restrict__ topi,
                                                    const float* __restrict__ tao_raw,
                                                    float* out) {
    __shared__ float tv[KNB]; __shared__ int ti[KNB]; __shared__ float w[KNB];
    __shared__ __align__(16) float aq2[272];
    __shared__ float red4[4];
    __shared__ float part[256];
    int i = blockIdx.x, t = threadIdx.x;
    const int lane = t & 63, wv = t >> 6;
    if (t < KNB) {
        tv[t] = topv[i * KNB + t];
        int j = topi[i * KNB + t];
        ti[t] = ((unsigned)j < NQ) ? j : 0;
    }
    __syncthreads();
    if (t < KNB) {
        int j = ti[t];
        bool mut = false;
        for (int s = 0; s < KNB; s++) mut = mut || (topi[j * KNB + s] == i);
        w[t] = mut ? tv[t] : -INFINITY;
    }
    __syncthreads();
    if (t < 16) {                               // wave-parallel softmax (10 live)
        float val = (t < KNB) ? w[t] : -INFINITY;
        float m = val;
        #pragma unroll
        for (int off = 8; off > 0; off >>= 1) m = fmaxf(m, __shfl_xor(m, off));
        float e = (t < KNB) ? expf(val - m) : 0.f;
        float Z = e;
        #pragma unroll
        for (int off = 8; off > 0; off >>= 1) Z += __shfl_xor(Z, off);
        if (t < KNB) w[t] = e / Z;
    }
    __syncthreads();
    float a = 0.f;
    for (int s = 0; s < KNB; s++) {
        float ws = w[s];
        if (ws != 0.f) a += ws * x[(long)qrow(ti[s]) * DD + t];
    }
    aq2[t + (t >> 6) * 4] = a;
    float v2 = a * a;
    #pragma unroll
    for (int off = 32; off > 0; off >>= 1) v2 += __shfl_xor(v2, off);
    if (lane == 0) red4[wv] = v2;
    __syncthreads();                            // publishes aq2 + red4
    float n2 = red4[0] + red4[1] + red4[2] + red4[3];
    float inv = 1.f / sqrtf(n2);
    int c = t >> 2, tl = t & 3;
    float sdot = 0.f;
    const float* aqb = aq2 + tl * 68;
    const float4* ap4 = (const float4*)(apn + c * DD + tl * 64);
    #pragma unroll
    for (int u4 = 0; u4 < 16; u4++) {
        float4 av = *(const float4*)(aqb + u4 * 4);
        float4 pv = ap4[u4];
        sdot += av.x * pv.x; sdot += av.y * pv.y; sdot += av.z * pv.z; sdot += av.w * pv.w;
    }
    part[t] = sdot; __syncthreads();
    if (tl == 0) {
        float sv = part[t] + part[t + 1] + part[t + 2] + part[t + 3];
        out[i * NCLS + c] = tao_raw[0] * sv * inv;
    }
}

extern "C" void kernel_launch(void* const* d_in, const int* in_sizes, int n_in,
                              void* d_out, int out_size, void* d_ws, size_t ws_size,
                              hipStream_t stream) {
    (void)in_sizes; (void)n_in; (void)out_size;
    const float* x   = (const float*)d_in[0];
    const float* tao = (const float*)d_in[1];
    float* out = (float*)d_out;

    char* ws = (char*)d_ws;
    size_t off = 0;
    auto carve = [&](size_t bytes) {
        void* p = ws + off;
        off = (off + bytes + 255) & ~(size_t)255;
        return p;
    };
    float*          proto   = (float*)carve(NCLS * DD * 4);
    float*          pn      = (float*)carve(NCLS * DD * 4);
    float*          selfs   = (float*)carve(NCLS * 4);
    float*          qInv    = (float*)carve(NQ * 4);
    float*          pre_max = (float*)carve(NQ * 4);
    int*            pre_lab = (int*)carve(NQ * 4);
    float*          apn     = (float*)carve(NCLS * DD * 4);
    unsigned short* xh      = (unsigned short*)carve((size_t)NQ * DD * 2);
    int*            topi4   = (int*)carve((size_t)NQ * CAND * 4);
    float*          topv    = (float*)carve((size_t)NQ * KNB * 4);
    int*            topi    = (int*)carve((size_t)NQ * KNB * 4);
    if (off > ws_size) return;

    proto_kernel<<<NCLS, 256, 0, stream>>>(x, proto, pn, selfs);
    presim_kernel<<<NQ, 256, 0, stream>>>(x, pn, xh, qInv, pre_max, pre_lab);
    adapt_proto_kernel<<<NCLS, 256, 0, stream>>>(x, proto, selfs, pre_max, pre_lab, apn);
    simtopk_kernel<<<NQ / 64 * NCH, 256, 0, stream>>>(xh, topi4);
    rescore_kernel<<<NQ, 256, 0, stream>>>(x, qInv, topi4, topv, topi);
    final_kernel<<<NQ, 256, 0, stream>>>(x, apn, topv, topi, tao, out);
}

// Round 14
// 363.758 us; speedup vs baseline: 1.1367x; 1.0347x over previous
//
#include <hip/hip_runtime.h>
#include <math.h>

#define NCLS 64
#define KS 5
#define DD 256
#define NQ 8192   // NCLS*128
#define KNB 10
#define QK 12     // per-chunk candidate list depth (need >=10 for exact containment)
#define NCH 8     // column chunks per row (1024 cols each)
#define CAND 96   // NCH * QK

typedef __attribute__((ext_vector_type(8))) short short8;   // 8 bf16 bit-patterns (4 VGPRs)
typedef __attribute__((ext_vector_type(4))) float f32x4;    // MFMA C/D frag

// row index in x (fp32 row units) of query g
__device__ __forceinline__ int qrow(int g) { return (g >> 7) * 133 + KS + (g & 127); }

__device__ __forceinline__ unsigned short bf16_rne(float f) {
    unsigned int u = __float_as_uint(f);
    u += 0x7fffu + ((u >> 16) & 1u);
    return (unsigned short)(u >> 16);
}

__device__ __forceinline__ float blk_reduce_sum(float v, float* red) {
    int t = threadIdx.x;
    red[t] = v; __syncthreads();
    for (int off = 128; off > 0; off >>= 1) {
        if (t < off) red[t] += red[t + off];
        __syncthreads();
    }
    float r = red[0];
    __syncthreads();
    return r;
}

__device__ __forceinline__ float blk_reduce_max(float v, float* red) {
    int t = threadIdx.x;
    red[t] = v; __syncthreads();
    for (int off = 128; off > 0; off >>= 1) {
        if (t < off) red[t] = fmaxf(red[t], red[t + off]);
        __syncthreads();
    }
    float r = red[0];
    __syncthreads();
    return r;
}

// ---------- K1: proto, pn, self_sim ----------
__global__ __launch_bounds__(256) void proto_kernel(const float* __restrict__ x,
                                                    float* proto, float* pn, float* selfs) {
    __shared__ float red[256];
    int c = blockIdx.x, t = threadIdx.x;
    float s = 0.f;
    for (int j = 0; j < KS; j++) s += x[(long)(c * 133 + j) * DD + t];
    float p = s / 5.0f;
    proto[c * DD + t] = p;
    float n2 = blk_reduce_sum(p * p, red);
    float pv = p / sqrtf(n2);
    pn[c * DD + t] = pv;
    float ss = blk_reduce_sum(pv * pv, red);
    if (t == 0) selfs[c] = ss;
}

// ---------- K2: FUSED split + pre_sim argmax — low-barrier version ----------
__global__ __launch_bounds__(256) void presim_kernel(const float* __restrict__ x,
                                                     const float* __restrict__ pn,
                                                     unsigned short* __restrict__ xh,
                                                     float* __restrict__ qInv,
                                                     float* pre_max, int* pre_label) {
    __shared__ __align__(16) float qs2[272];
    __shared__ float red4[4];
    __shared__ float part[256];
    __shared__ float sims[64];
    int g = blockIdx.x, t = threadIdx.x;
    const int lane = t & 63, wv = t >> 6;
    float v = x[(long)qrow(g) * DD + t];
    qs2[t + (t >> 6) * 4] = v;
    float v2 = v * v;
    #pragma unroll
    for (int off = 32; off > 0; off >>= 1) v2 += __shfl_xor(v2, off);
    if (lane == 0) red4[wv] = v2;
    __syncthreads();                               // publishes qs2 + red4
    float n2 = red4[0] + red4[1] + red4[2] + red4[3];
    float inv = 1.f / sqrtf(n2);
    xh[g * DD + t] = bf16_rne(v * inv);
    if (t == 0) qInv[g] = inv;
    int c = t >> 2, tl = t & 3;
    float s = 0.f;
    const float* qb = qs2 + tl * 68;
    const float4* pp = (const float4*)(pn + c * DD + tl * 64);
    #pragma unroll
    for (int u4 = 0; u4 < 16; u4++) {
        float4 a = *(const float4*)(qb + u4 * 4);
        float4 b = pp[u4];
        s += a.x * b.x; s += a.y * b.y; s += a.z * b.z; s += a.w * b.w;
    }
    part[t] = s; __syncthreads();
    if (tl == 0) sims[c] = part[t] + part[t + 1] + part[t + 2] + part[t + 3];
    __syncthreads();
    if (t < 64) {
        float bv = sims[t]; int bi = t;
        #pragma unroll
        for (int off = 32; off > 0; off >>= 1) {
            float ov = __shfl_xor(bv, off);
            int   oi = __shfl_xor(bi, off);
            bool take = (ov > bv) || (ov == bv && oi < bi);
            bv = take ? ov : bv;
            bi = take ? oi : bi;
        }
        if (t == 0) { pre_max[g] = bv * inv; pre_label[g] = bi; }
    }
}

// ---------- K3: adapted prototypes — LDS-compacted member list ----------
__global__ __launch_bounds__(256) void adapt_proto_kernel(const float* __restrict__ x,
                                                          const float* __restrict__ proto,
                                                          const float* __restrict__ selfs,
                                                          const float* __restrict__ pre_max,
                                                          const int* __restrict__ pre_label,
                                                          float* apn) {
    __shared__ int lst[NQ];
    __shared__ float red[256];
    __shared__ int cnt_s;
    int c = blockIdx.x, t = threadIdx.x;
    if (t == 0) cnt_s = 0;
    __syncthreads();
    float lm = -INFINITY;
    for (int g = t; g < NQ; g += 256) {
        if (pre_label[g] == c) {
            int p = atomicAdd(&cnt_s, 1);
            lst[p] = g;
            lm = fmaxf(lm, pre_max[g]);
        }
    }
    float m = fmaxf(blk_reduce_max(lm, red), selfs[c]);   // barrier publishes lst/cnt_s
    int cnt = cnt_s;
    float ls = 0.f;
    for (int e = t; e < cnt; e += 256) ls += expf(pre_max[lst[e]] - m);
    float es = expf(selfs[c] - m);
    float Z = blk_reduce_sum(ls, red) + es;
    float a0 = es * proto[c * DD + t], a1 = 0.f, a2 = 0.f, a3 = 0.f;
    int e = 0;
    for (; e + 3 < cnt; e += 4) {
        int g0 = lst[e], g1 = lst[e + 1], g2 = lst[e + 2], g3 = lst[e + 3];
        float w0 = expf(pre_max[g0] - m), w1 = expf(pre_max[g1] - m);
        float w2 = expf(pre_max[g2] - m), w3 = expf(pre_max[g3] - m);
        a0 += w0 * x[(long)qrow(g0) * DD + t];
        a1 += w1 * x[(long)qrow(g1) * DD + t];
        a2 += w2 * x[(long)qrow(g2) * DD + t];
        a3 += w3 * x[(long)qrow(g3) * DD + t];
    }
    for (; e < cnt; e++) {
        int g0 = lst[e];
        a0 += expf(pre_max[g0] - m) * x[(long)qrow(g0) * DD + t];
    }
    float ap = ((a0 + a1) + (a2 + a3)) / Z;
    float n2 = blk_reduce_sum(ap * ap, red);
    apn[c * DD + t] = ap / sqrtf(n2);
}

// ---------- K4: bf16 MFMA coarse cosines — BATCH-BITONIC top-12 scan ----------
// (R12 verified: simtopk off the top-5. Unchanged this round.)
#define CASD(A, B) { unsigned int _x = (A), _y = (B); (A) = _x > _y ? _x : _y; (B) = _x > _y ? _y : _x; }
#define CASA(A, B) { unsigned int _x = (A), _y = (B); (A) = _x < _y ? _x : _y; (B) = _x < _y ? _y : _x; }

#define COMPUTE_TILE_L(LBUF, TILE)                                                 \
    {                                                                              \
        f32x4 accE = {2.f, 2.f, 2.f, 2.f};                                         \
        f32x4 accO = {0.f, 0.f, 0.f, 0.f};                                         \
        _Pragma("unroll")                                                          \
        for (int kc = 0; kc < 8; kc += 2) {                                        \
            short8 cfe = *(const short8*)((LBUF) + ((nn << 8) + ((((kc + 0) * 4 + qd) ^ xm) << 3))); \
            short8 cfo = *(const short8*)((LBUF) + ((nn << 8) + ((((kc + 1) * 4 + qd) ^ xm) << 3))); \
            accE = __builtin_amdgcn_mfma_f32_16x16x32_bf16(cfe, qh[kc + 0], accE, 0, 0, 0); \
            accO = __builtin_amdgcn_mfma_f32_16x16x32_bf16(cfo, qh[kc + 1], accO, 0, 0, 0); \
        }                                                                          \
        const unsigned int cb_ = (unsigned int)((TILE) * 16 + 4 * qd);             \
        unsigned int v0 = (__float_as_uint(accE[0] + accO[0]) & 0xFFFFFC00u) | (cb_ + 0); \
        unsigned int v1 = (__float_as_uint(accE[1] + accO[1]) & 0xFFFFFC00u) | (cb_ + 1); \
        unsigned int v2 = (__float_as_uint(accE[2] + accO[2]) & 0xFFFFFC00u) | (cb_ + 2); \
        unsigned int v3 = (__float_as_uint(accE[3] + accO[3]) & 0xFFFFFC00u) | (cb_ + 3); \
        /* sort batch ascending: v0<=v1<=v2<=v3 */                                 \
        CASA(v0, v1) CASA(v2, v3) CASA(v0, v2) CASA(v1, v3) CASA(v1, v2)           \
        /* split16 (valley keys[0..11]++v[0..3]); (i,i+8) for i<4 are no-ops */    \
        unsigned int t4 = keys[4], t5 = keys[5], t6 = keys[6], t7 = keys[7];       \
        unsigned int b4 = t4 < v0 ? t4 : v0; t4 = t4 > v0 ? t4 : v0;               \
        unsigned int b5 = t5 < v1 ? t5 : v1; t5 = t5 > v1 ? t5 : v1;               \
        unsigned int b6 = t6 < v2 ? t6 : v2; t6 = t6 > v2 ? t6 : v2;               \
        unsigned int b7 = t7 < v3 ? t7 : v3; t7 = t7 > v3 ? t7 : v3;               \
        /* sort top-8 [keys0..3, t4..7] desc (bitonic) */                          \
        CASD(keys[0], t4) CASD(keys[1], t5) CASD(keys[2], t6) CASD(keys[3], t7)    \
        CASD(keys[0], keys[2]) CASD(keys[1], keys[3]) CASD(t4, t6) CASD(t5, t7)    \
        CASD(keys[0], keys[1]) CASD(keys[2], keys[3]) CASD(t4, t5) CASD(t6, t7)    \
        keys[4] = t4; keys[5] = t5; keys[6] = t6; keys[7] = t7;                    \
        /* bottom-8 [keys8..11, b4..7] bitonic: top-4 via split (max only) */      \
        unsigned int B0 = keys[8]  > b4 ? keys[8]  : b4;                           \
        unsigned int B1 = keys[9]  > b5 ? keys[9]  : b5;                           \
        unsigned int B2 = keys[10] > b6 ? keys[10] : b6;                           \
        unsigned int B3 = keys[11] > b7 ? keys[11] : b7;                           \
        CASD(B0, B2) CASD(B1, B3) CASD(B0, B1) CASD(B2, B3)                        \
        keys[8] = B0; keys[9] = B1; keys[10] = B2; keys[11] = B3;                  \
    }

#define GLOAD(RA, RB, TL)                                                          \
    {                                                                              \
        const unsigned short* tb = xh + ((size_t)(col0 + (TL) * 16) << 8);         \
        RA = *(const uint4*)(tb + (G0 << 3));                                      \
        RB = *(const uint4*)(tb + (G1 << 3));                                      \
    }

#define DSWRITE(P, RA, RB)                                                         \
    {                                                                              \
        *(uint4*)((P) + (u0 << 3)) = RA;                                           \
        *(uint4*)((P) + (u1 << 3)) = RB;                                           \
    }

__global__ __launch_bounds__(256, 4) void simtopk_kernel(const unsigned short* __restrict__ xh,
                                                         int* __restrict__ topi4) {
    __shared__ uint4 smem4[2048];   // 32 KB: 2 buffers x 2 tiles; dump alias 13.3KB
    unsigned short* Tb = (unsigned short*)smem4;

    const int t = threadIdx.x;
    const int b = blockIdx.x;
    const int rb = b >> 3;          // 128 row-blocks of 64 rows
    const int ch = b & 7;           // column chunk (== XCD id under round-robin: L2-local)
    const int row0 = rb * 64;
    const int col0 = ch * 1024;

    const int wv = t >> 6;
    const int lane = t & 63;
    const int qd = lane >> 4;
    const int nn = lane & 15;
    const int xm = nn & 7;

    // staging geometry: tile = 512 x 16B units; thread handles G0=t, G1=256+t
    const int G0 = t, G1 = 256 + t;
    const int r0r = G0 >> 5, c0u = G0 & 31;
    const int u0 = r0r * 32 + (c0u ^ (r0r & 7));
    const int r1r = G1 >> 5, c1u = G1 & 31;
    const int u1 = r1r * 32 + (c1u ^ (r1r & 7));

    // Query fragments (MFMA B operand): lane holds Q[n=nn][k=kc*32+qd*8 ..+7]
    const int arow = (row0 + wv * 16 + nn) * DD;
    short8 qh[8];
    #pragma unroll
    for (int kc = 0; kc < 8; kc++)
        qh[kc] = *(const short8*)(xh + arow + kc * 32 + qd * 8);

    unsigned int keys[QK];
    #pragma unroll
    for (int s = 0; s < QK; s++) keys[s] = 0u;

    uint4 RA, RB, RC, RD;
    GLOAD(RA, RB, 0)
    GLOAD(RC, RD, 1)
    DSWRITE(Tb, RA, RB)
    DSWRITE(Tb + 4096, RC, RD)
    __syncthreads();                         // tiles 0,1 ready in buffer 0

    #pragma unroll 1
    for (int p = 0; p < 32; ++p) {
        const int cur = (p & 1) << 13;       // 0 / 8192 shorts (16KB buffers)
        if (p < 31) { GLOAD(RA, RB, 2 * p + 2) GLOAD(RC, RD, 2 * p + 3) }
        COMPUTE_TILE_L(Tb + cur, 2 * p)
        COMPUTE_TILE_L(Tb + cur + 4096, 2 * p + 1)
        if (p < 31) {
            DSWRITE(Tb + (cur ^ 8192), RA, RB)
            DSWRITE(Tb + (cur ^ 8192) + 4096, RC, RD)
        }
        __syncthreads();                     // publishes pair p+1; orders reads of pair p
    }

    // dump (wave-private region, in-order DS: no barrier) + 4-list merge.
    unsigned int* dw = (unsigned int*)smem4 + wv * 832;
    #pragma unroll
    for (int s = 0; s < QK; s++) dw[lane * 13 + s] = keys[s];
    if (lane < 16) {
        const int g = row0 + wv * 16 + lane;
        const int b0 = (lane +  0) * 13;
        const int b1 = (lane + 16) * 13;
        const int b2 = (lane + 32) * 13;
        const int b3 = (lane + 48) * 13;
        int p0 = 0, p1 = 0, p2 = 0, p3 = 0;
        for (int s = 0; s < QK; s++) {
            unsigned int v0 = (p0 < QK) ? dw[b0 + p0] : 0u;
            unsigned int v1 = (p1 < QK) ? dw[b1 + p1] : 0u;
            unsigned int v2 = (p2 < QK) ? dw[b2 + p2] : 0u;
            unsigned int v3 = (p3 < QK) ? dw[b3 + p3] : 0u;
            unsigned int bv = v0; int bw = 0;
            if (v1 > bv) { bv = v1; bw = 1; }
            if (v2 > bv) { bv = v2; bw = 2; }
            if (v3 > bv) { bv = v3; bw = 3; }
            topi4[g * CAND + ch * QK + s] = col0 + (int)(bv & 1023u);
            if (bw == 0) p0++; else if (bw == 1) p1++; else if (bw == 2) p2++; else p3++;
        }
    }
}

// ---------- K5: FUSED exact fp32 rescoring + wave-parallel top-10 ----------
__global__ __launch_bounds__(256, 4) void rescore_kernel(const float* __restrict__ x,
                                                         const float* __restrict__ qInv,
                                                         const int* __restrict__ topi4,
                                                         float* __restrict__ topv,
                                                         int* __restrict__ topi) {
    __shared__ float sc[CAND];
    __shared__ int   si[CAND];
    const int g = blockIdx.x;
    const int t = threadIdx.x;
    const int lane = t & 63;
    const int w = t >> 6;            // wave's candidate group [24w, 24w+24)
    const float4 a4 = *(const float4*)(x + (long)qrow(g) * DD + lane * 4);
    const float qg = qInv[g];
    const int cb = g * CAND + w * 24;
    #pragma unroll 1
    for (int r = 0; r < 3; ++r) {
        const int c0 = cb + r * 8;
        int jj[8];
        #pragma unroll
        for (int u = 0; u < 8; u++) {
            int j = topi4[c0 + u];
            jj[u] = __builtin_amdgcn_readfirstlane(((unsigned)j < NQ) ? j : 0);
        }
        float4 b[8];
        #pragma unroll
        for (int u = 0; u < 8; u++)
            b[u] = *(const float4*)(x + (long)qrow(jj[u]) * DD + lane * 4);
        float p[8];
        #pragma unroll
        for (int u = 0; u < 8; u++)
            p[u] = a4.x * b[u].x + a4.y * b[u].y + a4.z * b[u].z + a4.w * b[u].w;
        #pragma unroll
        for (int off = 32; off > 0; off >>= 1) {
            #pragma unroll
            for (int u = 0; u < 8; u++) p[u] += __shfl_xor(p[u], off);
        }
        if (lane == 0) {
            const int cl = w * 24 + r * 8;
            #pragma unroll
            for (int u = 0; u < 8; u++) { sc[cl + u] = p[u] * qInv[jj[u]] * qg; si[cl + u] = jj[u]; }
        }
    }
    __syncthreads();
    if (t < 64) {
        float v0 = sc[lane];
        int   i0 = si[lane];
        float v1 = -INFINITY; int i1 = 0x7fffffff;
        if (lane < CAND - 64) { v1 = sc[64 + lane]; i1 = si[64 + lane]; }
        #pragma unroll 1
        for (int s = 0; s < KNB; ++s) {
            bool sel1 = (v1 > v0) || (v1 == v0 && i1 < i0);
            float bv = sel1 ? v1 : v0;
            int   bi = sel1 ? i1 : i0;
            #pragma unroll
            for (int off = 32; off > 0; off >>= 1) {
                float ov = __shfl_xor(bv, off);
                int   oi = __shfl_xor(bi, off);
                bool take = (ov > bv) || (ov == bv && oi < bi);
                bv = take ? ov : bv;
                bi = take ? oi : bi;
            }
            if (lane == 0) { topv[g * KNB + s] = bv; topi[g * KNB + s] = bi; }
            if (i0 == bi) v0 = -INFINITY;
            if (i1 == bi) v1 = -INFINITY;
        }
    }
}

// ---------- K6: mutual-kNN softmax, adapted query, final cos sims ----------
// R12 counters: VALUBusy 13.6%, occupancy 76% -> serial latency chain, not
// throughput. Two chains removed:
// (1) mutual check was `mut || load` short-circuit = 10 DEPENDENT scattered
//     loads per thread (~3000cyc). Now: 100 (s,u) pairs across 100 threads,
//     one load each, all in flight; flags OR-reduced in the softmax step.
// (2) row accumulation was guarded by `if(ws!=0)` (LDS-dependent) = 10
//     serial gathers. Now: w[]/ti[] preloaded to regs, 10 UNCONDITIONAL
//     loads batched (0*finite = 0 exactly -> bit-identical).
// __launch_bounds__(256,8): VGPR cap 64 so the 10 rows stay in flight.
__global__ __launch_bounds__(256, 8) void final_kernel(const float* __restrict__ x,
                                                       const float* __restrict__ apn,
                                                       const float* __restrict__ topv,
                                                       const int* __restrict__ topi,
                                                       const float* __restrict__ tao_raw,
                                                       float* out) {
    __shared__ float tv[KNB]; __shared__ int ti[KNB]; __shared__ float w[KNB];
    __shared__ int mutf[KNB * KNB];
    __shared__ __align__(16) float aq2[272];
    __shared__ float red4[4];
    __shared__ float part[256];
    int i = blockIdx.x, t = threadIdx.x;
    const int lane = t & 63, wv = t >> 6;
    if (t < KNB) {
        tv[t] = topv[i * KNB + t];
        int j = topi[i * KNB + t];
        ti[t] = ((unsigned)j < NQ) ? j : 0;
    }
    __syncthreads();
    if (t < KNB * KNB) {                        // parallel mutual: 100 loads in flight
        const int s = t / KNB, u = t - s * KNB;
        mutf[t] = (topi[ti[s] * KNB + u] == i) ? 1 : 0;
    }
    __syncthreads();
    if (t < 16) {                               // OR-reduce flags + wave softmax
        float val = -INFINITY;
        if (t < KNB) {
            const int* mf = &mutf[t * KNB];
            int any = mf[0] | mf[1] | mf[2] | mf[3] | mf[4]
                    | mf[5] | mf[6] | mf[7] | mf[8] | mf[9];
            val = any ? tv[t] : -INFINITY;
        }
        float m = val;
        #pragma unroll
        for (int off = 8; off > 0; off >>= 1) m = fmaxf(m, __shfl_xor(m, off));
        float e = (t < KNB) ? expf(val - m) : 0.f;
        float Z = e;
        #pragma unroll
        for (int off = 8; off > 0; off >>= 1) Z += __shfl_xor(Z, off);
        if (t < KNB) w[t] = e / Z;
    }
    __syncthreads();
    // preload weights + indices to registers, then batch all 10 row gathers
    float wr[KNB]; int tr[KNB];
    #pragma unroll
    for (int s = 0; s < KNB; s++) { wr[s] = w[s]; tr[s] = ti[s]; }
    float xv[KNB];
    #pragma unroll
    for (int s = 0; s < KNB; s++) xv[s] = x[(long)qrow(tr[s]) * DD + t];
    float a = 0.f;
    #pragma unroll
    for (int s = 0; s < KNB; s++) a += wr[s] * xv[s];
    aq2[t + (t >> 6) * 4] = a;
    float v2 = a * a;
    #pragma unroll
    for (int off = 32; off > 0; off >>= 1) v2 += __shfl_xor(v2, off);
    if (lane == 0) red4[wv] = v2;
    __syncthreads();                            // publishes aq2 + red4
    float n2 = red4[0] + red4[1] + red4[2] + red4[3];
    float inv = 1.f / sqrtf(n2);
    int c = t >> 2, tl = t & 3;
    float sdot = 0.f;
    const float* aqb = aq2 + tl * 68;
    const float4* ap4 = (const float4*)(apn + c * DD + tl * 64);
    #pragma unroll
    for (int u4 = 0; u4 < 16; u4++) {
        float4 av = *(const float4*)(aqb + u4 * 4);
        float4 pv = ap4[u4];
        sdot += av.x * pv.x; sdot += av.y * pv.y; sdot += av.z * pv.z; sdot += av.w * pv.w;
    }
    part[t] = sdot; __syncthreads();
    if (tl == 0) {
        float sv = part[t] + part[t + 1] + part[t + 2] + part[t + 3];
        out[i * NCLS + c] = tao_raw[0] * sv * inv;
    }
}

extern "C" void kernel_launch(void* const* d_in, const int* in_sizes, int n_in,
                              void* d_out, int out_size, void* d_ws, size_t ws_size,
                              hipStream_t stream) {
    (void)in_sizes; (void)n_in; (void)out_size;
    const float* x   = (const float*)d_in[0];
    const float* tao = (const float*)d_in[1];
    float* out = (float*)d_out;

    char* ws = (char*)d_ws;
    size_t off = 0;
    auto carve = [&](size_t bytes) {
        void* p = ws + off;
        off = (off + bytes + 255) & ~(size_t)255;
        return p;
    };
    float*          proto   = (float*)carve(NCLS * DD * 4);
    float*          pn      = (float*)carve(NCLS * DD * 4);
    float*          selfs   = (float*)carve(NCLS * 4);
    float*          qInv    = (float*)carve(NQ * 4);
    float*          pre_max = (float*)carve(NQ * 4);
    int*            pre_lab = (int*)carve(NQ * 4);
    float*          apn     = (float*)carve(NCLS * DD * 4);
    unsigned short* xh      = (unsigned short*)carve((size_t)NQ * DD * 2);
    int*            topi4   = (int*)carve((size_t)NQ * CAND * 4);
    float*          topv    = (float*)carve((size_t)NQ * KNB * 4);
    int*            topi    = (int*)carve((size_t)NQ * KNB * 4);
    if (off > ws_size) return;

    proto_kernel<<<NCLS, 256, 0, stream>>>(x, proto, pn, selfs);
    presim_kernel<<<NQ, 256, 0, stream>>>(x, pn, xh, qInv, pre_max, pre_lab);
    adapt_proto_kernel<<<NCLS, 256, 0, stream>>>(x, proto, selfs, pre_max, pre_lab, apn);
    simtopk_kernel<<<NQ / 64 * NCH, 256, 0, stream>>>(xh, topi4);
    rescore_kernel<<<NQ, 256, 0, stream>>>(x, qInv, topi4, topv, topi);
    final_kernel<<<NQ, 256, 0, stream>>>(x, apn, topv, topi, tao, out);
}